// Round 9
// baseline (423.993 us; speedup 1.0000x reference)
//
#include <hip/hip_runtime.h>
#include <math.h>

#define BB 64
#define TT 512
#define OBSD 115
#define DMD 128
#define DSD 8
#define NLD 3
#define EMBD 16
#define NAD 19
#define H1D 256
#define NTOK (BB*TT)
#define SSEG 32
#define TSEG (TT/SSEG)   // 16

typedef unsigned short ushort_t;
typedef __attribute__((ext_vector_type(8))) short short8;
typedef __attribute__((ext_vector_type(4))) float f32x4;

__device__ __forceinline__ float silu_f(float x){ return x / (1.f + __expf(-x)); }
__device__ __forceinline__ float softplus_f(float x){
  return fmaxf(x, 0.f) + log1pf(__expf(-fabsf(x)));
}
__device__ __forceinline__ ushort_t f2bf(float x){
  unsigned u = __float_as_uint(x);
  unsigned r = (u + 0x7fffu + ((u >> 16) & 1u)) >> 16;
  return (ushort_t)r;
}
__device__ __forceinline__ float b2f(ushort_t x){
  return __uint_as_float(((unsigned)x) << 16);
}
#define MFMA(a,b,c) __builtin_amdgcn_mfma_f32_16x16x32_bf16((a),(b),(c),0,0,0)
#define LOG2E 1.44269504f

// ---------------- k_prep ----------------
struct PJob { const float* src; ushort_t* dst; int N; int K; int Kpad; int rowofs; int Nw; };
struct PJobs { PJob j[20]; };

__global__ __launch_bounds__(256) void k_prep(PJobs P){
  const int job = blockIdx.x >> 2;
  const int sub = blockIdx.x & 3;
  PJob pj = P.j[job];
  const int elems = pj.Nw * pj.Kpad;
  for (int idx = sub*256 + threadIdx.x; idx < elems; idx += 4*256){
    int n = idx / pj.Kpad;
    int k = idx - n*pj.Kpad;
    float v = (n < pj.N && k < pj.K) ? pj.src[(size_t)n*pj.K + k] : 0.f;
    pj.dst[(size_t)(pj.rowofs + n)*pj.Kpad + k] = f2bf(v);
  }
}

// ======== k_enc12p: enc1+enc2+proj+LN(l0)+wig/wdbc(l0)+phaseA(l0), 16 tok/block ========
// (256,8): round-5 vs round-8 A/B showed (256,8)@VGPR32 = 97us beats (256,6)@VGPR40 = 102us;
// bank conflicts identical in both -> occupancy is the binding factor.
__global__ __launch_bounds__(256, 8) void k_enc12p(
    const float* __restrict__ obs, const ushort_t* __restrict__ w1b,
    const float* __restrict__ b1, const float* __restrict__ g1,
    const float* __restrict__ bb1,
    const ushort_t* __restrict__ w2b,
    const float* __restrict__ b2, const float* __restrict__ g2,
    const float* __restrict__ bb2,
    const float* __restrict__ emb, const int* __restrict__ pact,
    const ushort_t* __restrict__ pwb, const float* __restrict__ pb,
    const float* __restrict__ pg, const float* __restrict__ pbb,
    float* __restrict__ X,
    const float* __restrict__ lng, const float* __restrict__ lnb,
    const ushort_t* __restrict__ wigb, const ushort_t* __restrict__ wdbcb,
    const float* __restrict__ bdt,
    ushort_t* __restrict__ XINb, ushort_t* __restrict__ Zb,
    ushort_t* __restrict__ DTb, ushort_t* __restrict__ BTu, ushort_t* __restrict__ CTu,
    const float* __restrict__ alog0,
    float* __restrict__ HLOC, float* __restrict__ PPR)
{
  __shared__ __align__(16) char sm[15104];
  ushort_t* s_obs = (ushort_t*)sm;
  ushort_t* s_e1  = (ushort_t*)sm;
  ushort_t* s_xin = (ushort_t*)sm;
  ushort_t* s_dt  = (ushort_t*)(sm + 4352);
  ushort_t* s_a2  = (ushort_t*)(sm + 8448);
  ushort_t* s_btc = (ushort_t*)(sm + 13824);
  float2*   s_st  = (float2*)(sm + 14080);
  float2*   s_st2 = (float2*)(sm + 14592);

  const int tok0 = blockIdx.x * 16;
  const int bidx = blockIdx.x >> 5;
  const int ch   = blockIdx.x & 31;
  const int tid = threadIdx.x;
  const int lane = tid & 63, w = tid >> 6;
  const int q = lane >> 4, cn = lane & 15;

  // -- P1: stage obs (pad 115->128) + emb --
  {
    const int t = tid >> 4, kc = tid & 15;
    const float* op = obs + (size_t)(tok0 + t)*OBSD;
    short8 v;
    #pragma unroll
    for (int j = 0; j < 8; j++){
      int k = kc*8 + j;
      v[j] = (short)f2bf(k < OBSD ? op[k] : 0.f);
    }
    *(short8*)&s_obs[t*136 + kc*8] = v;
  }
  for (int e = tid; e < 16*32; e += 256){
    int t = e >> 5, k = e & 31;
    float v = 0.f;
    if (k < EMBD){ int a = pact[tok0 + t]; v = emb[(size_t)a*EMBD + k]; }
    s_a2[t*168 + 128 + k] = f2bf(v);
  }
  __syncthreads();

  // -- P2: GEMM1 (N=256, 4 tiles/wave) -> acc regs; in-reg LN stats --
  f32x4 acc[4];
  {
    short8 af[4];
    #pragma unroll
    for (int ks = 0; ks < 4; ks++)
      af[ks] = *(const short8*)&s_obs[cn*136 + ks*32 + q*8];
    #pragma unroll
    for (int nt = 0; nt < 4; nt++){
      const int n0 = (w*4 + nt) * 16;
      f32x4 a = {0.f,0.f,0.f,0.f};
      #pragma unroll
      for (int ks = 0; ks < 4; ks++){
        short8 bf = *(const short8*)&w1b[(size_t)(n0 + cn)*128 + ks*32 + q*8];
        a = MFMA(af[ks], bf, a);
      }
      float bv = b1[n0 + cn];
      #pragma unroll
      for (int r = 0; r < 4; r++) a[r] += bv;
      acc[nt] = a;
    }
    #pragma unroll
    for (int r = 0; r < 4; r++){
      float s = 0.f, s2 = 0.f;
      #pragma unroll
      for (int nt = 0; nt < 4; nt++){ float v = acc[nt][r]; s += v; s2 = fmaf(v, v, s2); }
      s += __shfl_xor(s, 1, 64); s2 += __shfl_xor(s2, 1, 64);
      s += __shfl_xor(s, 2, 64); s2 += __shfl_xor(s2, 2, 64);
      s += __shfl_xor(s, 4, 64); s2 += __shfl_xor(s2, 4, 64);
      s += __shfl_xor(s, 8, 64); s2 += __shfl_xor(s2, 8, 64);
      if (cn == 0) s_st[(q*4 + r)*4 + w] = make_float2(s, s2);
    }
  }
  __syncthreads();   // s_obs dead

  // -- P3: normalize(256) + silu -> s_e1 --
  {
    float mu[4], rs[4];
    #pragma unroll
    for (int r = 0; r < 4; r++){
      const int row = q*4 + r;
      float2 p0 = s_st[row*4+0], p1 = s_st[row*4+1];
      float2 p2 = s_st[row*4+2], p3 = s_st[row*4+3];
      float s = p0.x+p1.x+p2.x+p3.x, s2 = p0.y+p1.y+p2.y+p3.y;
      float m = s * (1.f/256.f);
      mu[r] = m;
      rs[r] = rsqrtf(s2 * (1.f/256.f) - m*m + 1e-5f);
    }
    #pragma unroll
    for (int nt = 0; nt < 4; nt++){
      const int col = (w*4 + nt)*16 + cn;
      float gg = g1[col], bbv = bb1[col];
      #pragma unroll
      for (int r = 0; r < 4; r++){
        float v = (acc[nt][r] - mu[r]) * rs[r] * gg + bbv;
        s_e1[(q*4 + r)*264 + col] = f2bf(silu_f(v));
      }
    }
  }
  __syncthreads();

  // -- P4: GEMM2 (K=256, N=128, 2 tiles/wave) -> acc2; stats --
  f32x4 acc2[2];
  {
    short8 af2[8];
    #pragma unroll
    for (int ks = 0; ks < 8; ks++)
      af2[ks] = *(const short8*)&s_e1[cn*264 + ks*32 + q*8];
    #pragma unroll
    for (int nt = 0; nt < 2; nt++){
      const int n0 = (w*2 + nt) * 16;
      f32x4 a = {0.f,0.f,0.f,0.f};
      #pragma unroll
      for (int ks = 0; ks < 8; ks++){
        short8 bf = *(const short8*)&w2b[(size_t)(n0 + cn)*256 + ks*32 + q*8];
        a = MFMA(af2[ks], bf, a);
      }
      float bv = b2[n0 + cn];
      #pragma unroll
      for (int r = 0; r < 4; r++) a[r] += bv;
      acc2[nt] = a;
    }
    #pragma unroll
    for (int r = 0; r < 4; r++){
      float s = 0.f, s2 = 0.f;
      #pragma unroll
      for (int nt = 0; nt < 2; nt++){ float v = acc2[nt][r]; s += v; s2 = fmaf(v, v, s2); }
      s += __shfl_xor(s, 1, 64); s2 += __shfl_xor(s2, 1, 64);
      s += __shfl_xor(s, 2, 64); s2 += __shfl_xor(s2, 2, 64);
      s += __shfl_xor(s, 4, 64); s2 += __shfl_xor(s2, 4, 64);
      s += __shfl_xor(s, 8, 64); s2 += __shfl_xor(s2, 8, 64);
      if (cn == 0) s_st[(q*4 + r)*4 + w] = make_float2(s, s2);
    }
  }
  __syncthreads();

  // -- P5: normalize(g2/bb2) -> s_a2 cols [0,128) --
  {
    float mu[4], rs[4];
    #pragma unroll
    for (int r = 0; r < 4; r++){
      const int row = q*4 + r;
      float2 p0 = s_st[row*4+0], p1 = s_st[row*4+1];
      float2 p2 = s_st[row*4+2], p3 = s_st[row*4+3];
      float s = p0.x+p1.x+p2.x+p3.x, s2 = p0.y+p1.y+p2.y+p3.y;
      float m = s * (1.f/128.f);
      mu[r] = m;
      rs[r] = rsqrtf(s2 * (1.f/128.f) - m*m + 1e-5f);
    }
    #pragma unroll
    for (int nt = 0; nt < 2; nt++){
      const int col = (w*2 + nt)*16 + cn;
      float gg = g2[col], bbv = bb2[col];
      #pragma unroll
      for (int r = 0; r < 4; r++){
        float v = (acc2[nt][r] - mu[r]) * rs[r] * gg + bbv;
        s_a2[(q*4 + r)*168 + col] = f2bf(v);
      }
    }
  }
  __syncthreads();

  // -- P6: proj GEMM (K=160) -> acc3; stats --
  f32x4 acc3[2];
  {
    short8 af3[5];
    #pragma unroll
    for (int ks = 0; ks < 5; ks++)
      af3[ks] = *(const short8*)&s_a2[cn*168 + ks*32 + q*8];
    #pragma unroll
    for (int nt = 0; nt < 2; nt++){
      const int n0 = (w*2 + nt) * 16;
      f32x4 a = {0.f,0.f,0.f,0.f};
      #pragma unroll
      for (int ks = 0; ks < 5; ks++){
        short8 bf = *(const short8*)&pwb[(size_t)(n0 + cn)*160 + ks*32 + q*8];
        a = MFMA(af3[ks], bf, a);
      }
      float bv = pb[n0 + cn];
      #pragma unroll
      for (int r = 0; r < 4; r++) a[r] += bv;
      acc3[nt] = a;
    }
    #pragma unroll
    for (int r = 0; r < 4; r++){
      float s = 0.f, s2 = 0.f;
      #pragma unroll
      for (int nt = 0; nt < 2; nt++){ float v = acc3[nt][r]; s += v; s2 = fmaf(v, v, s2); }
      s += __shfl_xor(s, 1, 64); s2 += __shfl_xor(s2, 1, 64);
      s += __shfl_xor(s, 2, 64); s2 += __shfl_xor(s2, 2, 64);
      s += __shfl_xor(s, 4, 64); s2 += __shfl_xor(s2, 4, 64);
      s += __shfl_xor(s, 8, 64); s2 += __shfl_xor(s2, 8, 64);
      if (cn == 0) s_st[(q*4 + r)*4 + w] = make_float2(s, s2);
    }
  }
  __syncthreads();

  // -- P7: normalize(pg/pbb)+silu -> acc3 + X; stats2 --
  {
    float mu[4], rs[4];
    #pragma unroll
    for (int r = 0; r < 4; r++){
      const int row = q*4 + r;
      float2 p0 = s_st[row*4+0], p1 = s_st[row*4+1];
      float2 p2 = s_st[row*4+2], p3 = s_st[row*4+3];
      float s = p0.x+p1.x+p2.x+p3.x, s2 = p0.y+p1.y+p2.y+p3.y;
      float m = s * (1.f/128.f);
      mu[r] = m;
      rs[r] = rsqrtf(s2 * (1.f/128.f) - m*m + 1e-5f);
    }
    float ps[4] = {0.f,0.f,0.f,0.f}, ps2[4] = {0.f,0.f,0.f,0.f};
    #pragma unroll
    for (int nt = 0; nt < 2; nt++){
      const int col = (w*2 + nt)*16 + cn;
      float gg = pg[col], bbv = pbb[col];
      #pragma unroll
      for (int r = 0; r < 4; r++){
        float v = (acc3[nt][r] - mu[r]) * rs[r] * gg + bbv;
        v = silu_f(v);
        acc3[nt][r] = v;
        X[(size_t)(tok0 + q*4 + r)*128 + col] = v;
        ps[r] += v; ps2[r] = fmaf(v, v, ps2[r]);
      }
    }
    #pragma unroll
    for (int r = 0; r < 4; r++){
      float s = ps[r], s2 = ps2[r];
      s += __shfl_xor(s, 1, 64); s2 += __shfl_xor(s2, 1, 64);
      s += __shfl_xor(s, 2, 64); s2 += __shfl_xor(s2, 2, 64);
      s += __shfl_xor(s, 4, 64); s2 += __shfl_xor(s2, 4, 64);
      s += __shfl_xor(s, 8, 64); s2 += __shfl_xor(s2, 8, 64);
      if (cn == 0) s_st2[(q*4 + r)*4 + w] = make_float2(s, s2);
    }
  }
  __syncthreads();

  // -- P8: mamba LN (lng/lnb) -> s_a2 cols [0,128) --
  {
    float mu[4], rs[4];
    #pragma unroll
    for (int r = 0; r < 4; r++){
      const int row = q*4 + r;
      float2 p0 = s_st2[row*4+0], p1 = s_st2[row*4+1];
      float2 p2 = s_st2[row*4+2], p3 = s_st2[row*4+3];
      float s = p0.x+p1.x+p2.x+p3.x, s2 = p0.y+p1.y+p2.y+p3.y;
      float m = s * (1.f/128.f);
      mu[r] = m;
      rs[r] = rsqrtf(s2 * (1.f/128.f) - m*m + 1e-5f);
    }
    #pragma unroll
    for (int nt = 0; nt < 2; nt++){
      const int col = (w*2 + nt)*16 + cn;
      float gg = lng[col], bbv = lnb[col];
      #pragma unroll
      for (int r = 0; r < 4; r++){
        float v = (acc3[nt][r] - mu[r]) * rs[r] * gg + bbv;
        s_a2[(q*4 + r)*168 + col] = f2bf(v);
      }
    }
  }
  __syncthreads();

  // -- P9: wig GEMM (N=256, 4 tiles/wave) --
  {
    short8 af[4];
    #pragma unroll
    for (int ks = 0; ks < 4; ks++)
      af[ks] = *(const short8*)&s_a2[cn*168 + ks*32 + q*8];
    #pragma unroll
    for (int i = 0; i < 4; i++){
      const int n0 = (w*4 + i) * 16;
      f32x4 a = {0.f,0.f,0.f,0.f};
      #pragma unroll
      for (int ks = 0; ks < 4; ks++){
        short8 bf = *(const short8*)&wigb[(size_t)(n0 + cn)*128 + ks*32 + q*8];
        a = MFMA(af[ks], bf, a);
      }
      if (n0 < 128){
        #pragma unroll
        for (int r = 0; r < 4; r++){
          int tr = q*4 + r;
          ushort_t bb = f2bf(a[r]);
          XINb[(size_t)(tok0 + tr)*128 + n0 + cn] = bb;
          s_xin[tr*136 + n0 + cn] = bb;
        }
      } else {
        #pragma unroll
        for (int r = 0; r < 4; r++){
          int tr = q*4 + r;
          Zb[(size_t)(tok0 + tr)*128 + (n0 - 128) + cn] = f2bf(a[r]);
        }
      }
    }
  }
  __syncthreads();

  // -- P10: wdbc GEMM (N=144, nt=w..9 step 4) --
  {
    short8 af2[4];
    #pragma unroll
    for (int ks = 0; ks < 4; ks++)
      af2[ks] = *(const short8*)&s_xin[cn*136 + ks*32 + q*8];
    for (int nt = w; nt < 9; nt += 4){
      const int n0 = nt * 16;
      f32x4 a = {0.f,0.f,0.f,0.f};
      #pragma unroll
      for (int ks = 0; ks < 4; ks++){
        short8 bf = *(const short8*)&wdbcb[(size_t)(n0 + cn)*128 + ks*32 + q*8];
        a = MFMA(af2[ks], bf, a);
      }
      const int col = n0 + cn;
      if (col < 128){
        float bd = bdt[col];
        #pragma unroll
        for (int r = 0; r < 4; r++){
          int tr = q*4 + r;
          ushort_t dv = f2bf(softplus_f(a[r] + bd));
          DTb[(size_t)(tok0 + tr)*128 + col] = dv;
          s_dt[tr*136 + col] = dv;
        }
      } else if (col < 136){
        #pragma unroll
        for (int r = 0; r < 4; r++){
          int tr = q*4 + r;
          ushort_t bb = f2bf(a[r]);
          BTu[(size_t)(tok0 + tr)*8 + (col - 128)] = bb;
          s_btc[tr*8 + (col - 128)] = bb;
        }
      } else {
        #pragma unroll
        for (int r = 0; r < 4; r++)
          CTu[(size_t)(tok0 + q*4 + r)*8 + (col - 136)] = f2bf(a[r]);
      }
    }
  }
  __syncthreads();

  // -- P11: phase A (layer 0): thread=(d, s-half), 4 states, 16 tokens --
  {
    const int d = tid & 127, sh = tid >> 7;
    float A2c[4], hh[4], pp[4];
    #pragma unroll
    for (int j = 0; j < 4; j++){
      A2c[j] = -__expf(alog0[d*8 + sh*4 + j]) * LOG2E;
      hh[j] = 0.f; pp[j] = 1.f;
    }
    #pragma unroll 4
    for (int t = 0; t < 16; t++){
      float dt = b2f(s_dt[t*136 + d]);
      float wv = dt * b2f(s_xin[t*136 + d]);
      #pragma unroll
      for (int j = 0; j < 4; j++){
        float dA = exp2f(dt * A2c[j]);
        hh[j] = fmaf(dA, hh[j], wv * b2f(s_btc[t*8 + sh*4 + j]));
        pp[j] *= dA;
      }
    }
    const size_t o = ((size_t)bidx*SSEG + ch)*1024 + d*8 + sh*4;
    #pragma unroll
    for (int j = 0; j < 4; j++){ HLOC[o+j] = hh[j]; PPR[o+j] = pp[j]; }
  }
}

// ======== phase B over 16 tokens: in-block carry prefix + all-wave scan + wout + LN ====
// Carry-in computed per block from raw chunk-local (HL,PP): h = h0; for ch<seg: h=pp*h+hl.
// HL/PP total 32MB -> L3-resident; each thread reads only its own 8 floats/chunk.
// LDS (bytes):
//  [0,4096) s_dtS ; [4096,8192) s_xiS ; [8192,12288) s_zS   [dead after scan]
//  [0,8320)      s_x f32 16x130 (wout out; aliases staging)
//  [0,4352)      s_xin bf16 (wig out, late) ; [4352,8704) s_dt2 (wdbc out, late)
//  [12288,16640) s_a bf16 16x136
//  [16640,16896) s_bt ; [16896,17152) s_ct
//  [17152,17664) s_st float2[16][4]
#define SMB 17664

__device__ __forceinline__ void phaseB16(
    const ushort_t* DTb, const ushort_t* XINb, const ushort_t* Zb,
    const ushort_t* BTu, const ushort_t* CTu,
    const float* __restrict__ alog,
    const float* __restrict__ HLpre, const float* __restrict__ PPpre,
    const float* __restrict__ h0g,
    const float* __restrict__ dpar, const ushort_t* __restrict__ woutb,
    float* __restrict__ X, char* sm, int b, int seg, int tid)
{
  ushort_t* s_dtS = (ushort_t*)sm;
  ushort_t* s_xiS = (ushort_t*)(sm + 4096);
  ushort_t* s_zS  = (ushort_t*)(sm + 8192);
  float*    s_x   = (float*)sm;
  ushort_t* s_a   = (ushort_t*)(sm + 12288);
  ushort_t* s_bt  = (ushort_t*)(sm + 16640);
  ushort_t* s_ct  = (ushort_t*)(sm + 16896);
  float2*   s_st  = (float2*)(sm + 17152);

  const int lane = tid & 63, w = tid >> 6, q = lane >> 4, cn = lane & 15;
  const size_t segtok = (size_t)b*TT + seg*TSEG;

  // stage dt/xin/z (16x128 bf16 each = 256 uint4) + bt/ct
  ((uint4*)s_dtS)[tid] = ((const uint4*)(DTb  + segtok*128))[tid];
  ((uint4*)s_xiS)[tid] = ((const uint4*)(XINb + segtok*128))[tid];
  ((uint4*)s_zS )[tid] = ((const uint4*)(Zb   + segtok*128))[tid];
  if (tid < 64){
    ((unsigned*)s_bt)[tid] = ((const unsigned*)(BTu + segtok*8))[tid];
    ((unsigned*)s_ct)[tid] = ((const unsigned*)(CTu + segtok*8))[tid];
  }

  // recurrence state: all 256 threads; (d2, sh) = (w*32 + lane&31, lane>>5)
  const int d2 = (w << 5) | (lane & 31);
  const int sh = lane >> 5;
  float A2h[4], h[4];
  {
    #pragma unroll
    for (int j = 0; j < 4; j++)
      A2h[j] = -__expf(alog[d2*8 + sh*4 + j]) * LOG2E;
    // carry-in: h0 combined over chunks < seg (4x-unrolled so loads pipeline)
    float4 hv = *(const float4*)(h0g + (size_t)b*1024 + d2*8 + sh*4);
    h[0]=hv.x; h[1]=hv.y; h[2]=hv.z; h[3]=hv.w;
    const size_t cb = (size_t)b*(SSEG*1024) + d2*8 + sh*4;
    int ch = 0;
    for (; ch + 4 <= seg; ch += 4){
      float4 hl0 = *(const float4*)(HLpre + cb + (size_t)(ch+0)*1024);
      float4 pp0 = *(const float4*)(PPpre + cb + (size_t)(ch+0)*1024);
      float4 hl1 = *(const float4*)(HLpre + cb + (size_t)(ch+1)*1024);
      float4 pp1 = *(const float4*)(PPpre + cb + (size_t)(ch+1)*1024);
      float4 hl2 = *(const float4*)(HLpre + cb + (size_t)(ch+2)*1024);
      float4 pp2 = *(const float4*)(PPpre + cb + (size_t)(ch+2)*1024);
      float4 hl3 = *(const float4*)(HLpre + cb + (size_t)(ch+3)*1024);
      float4 pp3 = *(const float4*)(PPpre + cb + (size_t)(ch+3)*1024);
      h[0]=fmaf(pp0.x,h[0],hl0.x); h[1]=fmaf(pp0.y,h[1],hl0.y);
      h[2]=fmaf(pp0.z,h[2],hl0.z); h[3]=fmaf(pp0.w,h[3],hl0.w);
      h[0]=fmaf(pp1.x,h[0],hl1.x); h[1]=fmaf(pp1.y,h[1],hl1.y);
      h[2]=fmaf(pp1.z,h[2],hl1.z); h[3]=fmaf(pp1.w,h[3],hl1.w);
      h[0]=fmaf(pp2.x,h[0],hl2.x); h[1]=fmaf(pp2.y,h[1],hl2.y);
      h[2]=fmaf(pp2.z,h[2],hl2.z); h[3]=fmaf(pp2.w,h[3],hl2.w);
      h[0]=fmaf(pp3.x,h[0],hl3.x); h[1]=fmaf(pp3.y,h[1],hl3.y);
      h[2]=fmaf(pp3.z,h[2],hl3.z); h[3]=fmaf(pp3.w,h[3],hl3.w);
    }
    for (; ch < seg; ch++){
      float4 hl = *(const float4*)(HLpre + cb + (size_t)ch*1024);
      float4 pp = *(const float4*)(PPpre + cb + (size_t)ch*1024);
      h[0]=fmaf(pp.x,h[0],hl.x); h[1]=fmaf(pp.y,h[1],hl.y);
      h[2]=fmaf(pp.z,h[2],hl.z); h[3]=fmaf(pp.w,h[3],hl.w);
    }
  }
  const float dp = dpar[d2];
  __syncthreads();

  // scan: 4 states/thread; cross-half y combine via shfl_xor 32
  #pragma unroll 4
  for (int t = 0; t < 16; t++){
    float dt = b2f(s_dtS[t*128 + d2]);
    float xi = b2f(s_xiS[t*128 + d2]);
    float zv = b2f(s_zS [t*128 + d2]);
    float wv = dt * xi;
    float yp = 0.f;
    #pragma unroll
    for (int j = 0; j < 4; j++){
      float dA = exp2f(dt * A2h[j]);
      h[j] = fmaf(dA, h[j], wv * b2f(s_bt[t*8 + sh*4 + j]));
      yp = fmaf(h[j], b2f(s_ct[t*8 + sh*4 + j]), yp);
    }
    float y = yp + __shfl_xor(yp, 32, 64);
    float ssm = y * silu_f(zv) + xi * dp;
    if (sh == 0) s_a[t*136 + d2] = f2bf(ssm);
  }
  __syncthreads();   // staging dead; s_x writable

  // wout GEMM (N=128, 2 tiles/wave) + residual -> s_x + X; in-reg LN stats
  {
    short8 af[4];
    #pragma unroll
    for (int ks = 0; ks < 4; ks++)
      af[ks] = *(const short8*)&s_a[cn*136 + ks*32 + q*8];
    float ps[4] = {0.f,0.f,0.f,0.f}, ps2[4] = {0.f,0.f,0.f,0.f};
    #pragma unroll
    for (int i = 0; i < 2; i++){
      const int n0 = (w*2 + i) * 16;
      short8 bf[4];
      #pragma unroll
      for (int ks = 0; ks < 4; ks++)
        bf[ks] = *(const short8*)&woutb[(size_t)(n0+cn)*128 + ks*32 + q*8];
      f32x4 acc = {0.f,0.f,0.f,0.f};
      #pragma unroll
      for (int ks = 0; ks < 4; ks++) acc = MFMA(af[ks], bf[ks], acc);
      #pragma unroll
      for (int r = 0; r < 4; r++){
        const int tr = q*4 + r;
        const size_t g = (segtok + tr)*128 + n0 + cn;
        float xn = X[g] + acc[r];
        X[g] = xn;
        s_x[tr*130 + n0 + cn] = xn;
        ps[r] += xn; ps2[r] = fmaf(xn, xn, ps2[r]);
      }
    }
    #pragma unroll
    for (int r = 0; r < 4; r++){
      float s = ps[r], s2 = ps2[r];
      s += __shfl_xor(s, 1, 64); s2 += __shfl_xor(s2, 1, 64);
      s += __shfl_xor(s, 2, 64); s2 += __shfl_xor(s2, 2, 64);
      s += __shfl_xor(s, 4, 64); s2 += __shfl_xor(s2, 4, 64);
      s += __shfl_xor(s, 8, 64); s2 += __shfl_xor(s2, 8, 64);
      if (cn == 0) s_st[(q*4 + r)*4 + w] = make_float2(s, s2);
    }
  }
  __syncthreads();
}

// ---- k_scan2p: 16-token block; phaseB(+carry), LN, wig, wdbc, phaseA(next) ----
__global__ __launch_bounds__(256, 6) void k_scan2p(
    ushort_t* DTb, ushort_t* XINb, ushort_t* Zb,
    ushort_t* BTu, ushort_t* CTu,
    const float* __restrict__ alog,
    const float* __restrict__ HLpre, const float* __restrict__ PPpre,
    const float* __restrict__ h0g,
    const float* __restrict__ dpar, const ushort_t* __restrict__ woutb,
    float* __restrict__ X,
    const float* __restrict__ lng, const float* __restrict__ lnb,
    const ushort_t* __restrict__ wigb, const ushort_t* __restrict__ wdbcb,
    const float* __restrict__ bdt,
    const float* __restrict__ alogn,
    float* __restrict__ HLo, float* __restrict__ PPo)
{
  __shared__ __align__(16) char sm[SMB];
  const int tid = threadIdx.x;
  float*    s_x   = (float*)sm;
  ushort_t* s_xin = (ushort_t*)sm;
  ushort_t* s_dt2 = (ushort_t*)(sm + 4352);
  ushort_t* s_a   = (ushort_t*)(sm + 12288);
  ushort_t* s_btc = (ushort_t*)(sm + 16640);
  float2*   s_st  = (float2*)(sm + 17152);

  const int b = blockIdx.x >> 5;
  const int seg = blockIdx.x & 31;
  const int lane = tid & 63, w = tid >> 6, q = lane >> 4, cn = lane & 15;
  const size_t segtok = (size_t)b*TT + seg*TSEG;

  phaseB16(DTb, XINb, Zb, BTu, CTu, alog, HLpre, PPpre, h0g, dpar, woutb, X, sm, b, seg, tid);

  // P4: normalize (lng/lnb) -> s_a
  {
    const int d = tid & 127, half = tid >> 7;
    float g = lng[d], c0v = lnb[d];
    #pragma unroll
    for (int tt = 0; tt < 8; tt++){
      const int t = half*8 + tt;
      float2 p0 = s_st[t*4+0], p1 = s_st[t*4+1];
      float2 p2 = s_st[t*4+2], p3 = s_st[t*4+3];
      float ssum = p0.x+p1.x+p2.x+p3.x, ss2 = p0.y+p1.y+p2.y+p3.y;
      float mu = ssum * (1.f/128.f);
      float rs = rsqrtf(ss2 * (1.f/128.f) - mu*mu + 1e-5f);
      float v = (s_x[t*130 + d] - mu) * rs * g + c0v;
      s_a[t*136 + d] = f2bf(v);
    }
  }
  __syncthreads();

  // P5: wig GEMM (N=256, 4 tiles/wave); writes s_xin (aliases dead s_x) + XINb/Zb
  {
    short8 af[4];
    #pragma unroll
    for (int ks = 0; ks < 4; ks++)
      af[ks] = *(const short8*)&s_a[cn*136 + ks*32 + q*8];
    #pragma unroll
    for (int i = 0; i < 4; i++){
      const int n0 = (w*4 + i) * 16;
      short8 bf[4];
      #pragma unroll
      for (int ks = 0; ks < 4; ks++)
        bf[ks] = *(const short8*)&wigb[(size_t)(n0+cn)*128 + ks*32 + q*8];
      f32x4 acc = {0.f,0.f,0.f,0.f};
      #pragma unroll
      for (int ks = 0; ks < 4; ks++) acc = MFMA(af[ks], bf[ks], acc);
      if (n0 < 128){
        #pragma unroll
        for (int r = 0; r < 4; r++){
          const int tr = q*4 + r;
          ushort_t bb = f2bf(acc[r]);
          XINb[(segtok + tr)*128 + n0 + cn] = bb;
          s_xin[tr*136 + n0 + cn] = bb;
        }
      } else {
        #pragma unroll
        for (int r = 0; r < 4; r++){
          const int tr = q*4 + r;
          Zb[(segtok + tr)*128 + (n0-128) + cn] = f2bf(acc[r]);
        }
      }
    }
  }
  __syncthreads();

  // P6: wdbc GEMM; fills s_dt2 / s_btc
  {
    short8 af2[4];
    #pragma unroll
    for (int ks = 0; ks < 4; ks++)
      af2[ks] = *(const short8*)&s_xin[cn*136 + ks*32 + q*8];
    for (int nt = w; nt < 9; nt += 4){
      const int n0 = nt * 16;
      short8 bf[4];
      #pragma unroll
      for (int ks = 0; ks < 4; ks++)
        bf[ks] = *(const short8*)&wdbcb[(size_t)(n0+cn)*128 + ks*32 + q*8];
      f32x4 acc = {0.f,0.f,0.f,0.f};
      #pragma unroll
      for (int ks = 0; ks < 4; ks++) acc = MFMA(af2[ks], bf[ks], acc);
      const int col = n0 + cn;
      if (col < 128){
        float bd = bdt[col];
        #pragma unroll
        for (int r = 0; r < 4; r++){
          const int tr = q*4 + r;
          ushort_t dv = f2bf(softplus_f(acc[r] + bd));
          DTb[(segtok + tr)*128 + col] = dv;
          s_dt2[tr*136 + col] = dv;
        }
      } else if (col < 136){
        #pragma unroll
        for (int r = 0; r < 4; r++){
          const int tr = q*4 + r;
          ushort_t bb = f2bf(acc[r]);
          BTu[(segtok + tr)*8 + (col-128)] = bb;
          s_btc[tr*8 + (col-128)] = bb;
        }
      } else {
        #pragma unroll
        for (int r = 0; r < 4; r++)
          CTu[(segtok + q*4 + r)*8 + (col-136)] = f2bf(acc[r]);
      }
    }
  }
  __syncthreads();

  // P7: phase A (next layer): thread=(d, s-half), 4 states, 16 tokens
  {
    const int d = tid & 127, sh = tid >> 7;
    float A2n[4], hh[4], pp[4];
    #pragma unroll
    for (int j = 0; j < 4; j++){
      A2n[j] = -__expf(alogn[d*8 + sh*4 + j]) * LOG2E;
      hh[j] = 0.f; pp[j] = 1.f;
    }
    #pragma unroll 4
    for (int t = 0; t < 16; t++){
      float dt = b2f(s_dt2[t*136 + d]);
      float wv = dt * b2f(s_xin[t*136 + d]);
      #pragma unroll
      for (int j = 0; j < 4; j++){
        float dA = exp2f(dt * A2n[j]);
        hh[j] = fmaf(dA, hh[j], wv * b2f(s_btc[t*8 + sh*4 + j]));
        pp[j] *= dA;
      }
    }
    const size_t o = ((size_t)b*SSEG + seg)*1024 + d*8 + sh*4;
    #pragma unroll
    for (int j = 0; j < 4; j++){ HLo[o+j] = hh[j]; PPo[o+j] = pp[j]; }
  }
}

// ---- k_scan2h: 16-token block; phaseB(+carry), LNfn, pw1(+stats), LN+silu, pw2 ----
__global__ __launch_bounds__(256, 6) void k_scan2h(
    const ushort_t* DTb, const ushort_t* XINb, const ushort_t* Zb,
    const ushort_t* BTu, const ushort_t* CTu,
    const float* __restrict__ alog,
    const float* __restrict__ HLpre, const float* __restrict__ PPpre,
    const float* __restrict__ h0g,
    const float* __restrict__ dpar, const ushort_t* __restrict__ woutb,
    float* __restrict__ X,
    const float* __restrict__ fng, const float* __restrict__ fnb,
    const ushort_t* __restrict__ pw1b, const float* __restrict__ pb1,
    const float* __restrict__ pg, const float* __restrict__ pbb,
    const ushort_t* __restrict__ pw2b, const float* __restrict__ pb2,
    float* __restrict__ out)
{
  __shared__ __align__(16) char sm[SMB];
  const int tid = threadIdx.x;
  float*    s_x  = (float*)sm;
  ushort_t* s_a  = (ushort_t*)(sm + 12288);
  float2*   s_st = (float2*)(sm + 17152);

  const int b = blockIdx.x >> 5;
  const int seg = blockIdx.x & 31;
  const int lane = tid & 63, w = tid >> 6, q = lane >> 4, cn = lane & 15;
  const size_t segtok = (size_t)b*TT + seg*TSEG;

  phaseB16((ushort_t*)DTb, (ushort_t*)XINb, (ushort_t*)Zb,
           (ushort_t*)BTu, (ushort_t*)CTu, alog, HLpre, PPpre, h0g,
           dpar, woutb, X, sm, b, seg, tid);

  // P4: LN_fn -> s_a
  {
    const int d = tid & 127, half = tid >> 7;
    float g = fng[d], c0v = fnb[d];
    #pragma unroll
    for (int tt = 0; tt < 8; tt++){
      const int t = half*8 + tt;
      float2 p0 = s_st[t*4+0], p1 = s_st[t*4+1];
      float2 p2 = s_st[t*4+2], p3 = s_st[t*4+3];
      float ssum = p0.x+p1.x+p2.x+p3.x, ss2 = p0.y+p1.y+p2.y+p3.y;
      float mu = ssum * (1.f/128.f);
      float rs = rsqrtf(ss2 * (1.f/128.f) - mu*mu + 1e-5f);
      float v = (s_x[t*130 + d] - mu) * rs * g + c0v;
      s_a[t*136 + d] = f2bf(v);
    }
  }
  __syncthreads();

  // P5: pw1 GEMM (N=128, 2 tiles/wave) -> s_x (+bias); in-reg stats
  {
    short8 af[4];
    #pragma unroll
    for (int ks = 0; ks < 4; ks++)
      af[ks] = *(const short8*)&s_a[cn*136 + ks*32 + q*8];
    float ps[4] = {0.f,0.f,0.f,0.f}, ps2[4] = {0.f,0.f,0.f,0.f};
    #pragma unroll
    for (int i = 0; i < 2; i++){
      const int n0 = (w*2 + i) * 16;
      short8 bf[4];
      #pragma unroll
      for (int ks = 0; ks < 4; ks++)
        bf[ks] = *(const short8*)&pw1b[(size_t)(n0+cn)*128 + ks*32 + q*8];
      float bias = pb1[n0 + cn];
      f32x4 acc = {0.f,0.f,0.f,0.f};
      #pragma unroll
      for (int ks = 0; ks < 4; ks++) acc = MFMA(af[ks], bf[ks], acc);
      #pragma unroll
      for (int r = 0; r < 4; r++){
        float xv = acc[r] + bias;
        s_x[(q*4 + r)*130 + n0 + cn] = xv;
        ps[r] += xv; ps2[r] = fmaf(xv, xv, ps2[r]);
      }
    }
    #pragma unroll
    for (int r = 0; r < 4; r++){
      float s = ps[r], s2 = ps2[r];
      s += __shfl_xor(s, 1, 64); s2 += __shfl_xor(s2, 1, 64);
      s += __shfl_xor(s, 2, 64); s2 += __shfl_xor(s2, 2, 64);
      s += __shfl_xor(s, 4, 64); s2 += __shfl_xor(s2, 4, 64);
      s += __shfl_xor(s, 8, 64); s2 += __shfl_xor(s2, 8, 64);
      if (cn == 0) s_st[(q*4 + r)*4 + w] = make_float2(s, s2);
    }
  }
  __syncthreads();

  // P6: LN(pg/pbb)+silu -> s_a
  {
    const int d = tid & 127, half = tid >> 7;
    float g = pg[d], c0v = pbb[d];
    #pragma unroll
    for (int tt = 0; tt < 8; tt++){
      const int t = half*8 + tt;
      float2 p0 = s_st[t*4+0], p1 = s_st[t*4+1];
      float2 p2 = s_st[t*4+2], p3 = s_st[t*4+3];
      float ssum = p0.x+p1.x+p2.x+p3.x, ss2 = p0.y+p1.y+p2.y+p3.y;
      float mu = ssum * (1.f/128.f);
      float rs = rsqrtf(ss2 * (1.f/128.f) - mu*mu + 1e-5f);
      float v = (s_x[t*130 + d] - mu) * rs * g + c0v;
      s_a[t*136 + d] = f2bf(silu_f(v));
    }
  }
  __syncthreads();

  // P7: pw2 GEMM (N=32; waves 0,1; cols<19 stored)
  if (w < 2){
    short8 af[4];
    #pragma unroll
    for (int ks = 0; ks < 4; ks++)
      af[ks] = *(const short8*)&s_a[cn*136 + ks*32 + q*8];
    const int n0 = w * 16;
    short8 bf[4];
    #pragma unroll
    for (int ks = 0; ks < 4; ks++)
      bf[ks] = *(const short8*)&pw2b[(size_t)(n0+cn)*128 + ks*32 + q*8];
    const int col = n0 + cn;
    f32x4 acc = {0.f,0.f,0.f,0.f};
    #pragma unroll
    for (int ks = 0; ks < 4; ks++) acc = MFMA(af[ks], bf[ks], acc);
    if (col < NAD){
      float bias = pb2[col];
      #pragma unroll
      for (int r = 0; r < 4; r++)
        out[(segtok + q*4 + r)*NAD + col] = acc[r] + bias;
    }
  }
}

extern "C" void kernel_launch(void* const* d_in, const int* in_sizes, int n_in,
                              void* d_out, int out_size, void* d_ws, size_t ws_size,
                              hipStream_t stream) {
  const float* obs    = (const float*)d_in[0];
  const float* h0     = (const float*)d_in[1];
  const float* enc_w1 = (const float*)d_in[2];
  const float* enc_b1 = (const float*)d_in[3];
  const float* enc_g1 = (const float*)d_in[4];
  const float* enc_bb1= (const float*)d_in[5];
  const float* enc_w2 = (const float*)d_in[6];
  const float* enc_b2 = (const float*)d_in[7];
  const float* enc_g2 = (const float*)d_in[8];
  const float* enc_bb2= (const float*)d_in[9];
  const float* emb    = (const float*)d_in[10];
  const float* proj_w = (const float*)d_in[11];
  const float* proj_b = (const float*)d_in[12];
  const float* proj_g = (const float*)d_in[13];
  const float* proj_bb= (const float*)d_in[14];
  const float* m_ln_g = (const float*)d_in[15];
  const float* m_ln_b = (const float*)d_in[16];
  const float* m_w_ig = (const float*)d_in[17];
  const float* m_w_dt = (const float*)d_in[18];
  const float* m_b_dt = (const float*)d_in[19];
  const float* m_a_log= (const float*)d_in[20];
  const float* m_w_b  = (const float*)d_in[21];
  const float* m_w_c  = (const float*)d_in[22];
  const float* m_d    = (const float*)d_in[23];
  const float* m_w_out= (const float*)d_in[24];
  const float* fn_g   = (const float*)d_in[25];
  const float* fn_b   = (const float*)d_in[26];
  const float* pol_w1 = (const float*)d_in[27];
  const float* pol_b1 = (const float*)d_in[28];
  const float* pol_g  = (const float*)d_in[29];
  const float* pol_bb = (const float*)d_in[30];
  const float* pol_w2 = (const float*)d_in[31];
  const float* pol_b2 = (const float*)d_in[32];
  const int*   pact   = (const int*)d_in[33];

  float* ws  = (float*)d_ws;
  float* X    = ws;
  float* HLA  = X + (size_t)NTOK*128;
  float* PPA  = HLA + (size_t)BB*SSEG*1024;
  float* HLB  = PPA + (size_t)BB*SSEG*1024;
  float* PPB  = HLB + (size_t)BB*SSEG*1024;
  ushort_t* XINb = (ushort_t*)(PPB + (size_t)BB*SSEG*1024);
  ushort_t* Zb   = XINb + (size_t)NTOK*128;
  ushort_t* DTb  = Zb   + (size_t)NTOK*128;
  ushort_t* BTu  = DTb  + (size_t)NTOK*128;
  ushort_t* CTu  = BTu  + (size_t)NTOK*8;

  ushort_t* W1B   = CTu   + (size_t)NTOK*8;
  ushort_t* W2B   = W1B   + 256*128;
  ushort_t* PWB   = W2B   + 128*256;
  ushort_t* WIGB  = PWB   + 128*160;
  ushort_t* WDBCB = WIGB  + 3*256*128;
  ushort_t* WOUTB = WDBCB + 3*144*128;
  ushort_t* PW1B  = WOUTB + 3*128*128;
  ushort_t* PW2B  = PW1B  + 128*128;

  PJobs P;
  int nj = 0;
  auto add = [&](const float* src, ushort_t* dst, int N, int K, int Kpad, int rowofs, int Nw){
    P.j[nj].src = src; P.j[nj].dst = dst; P.j[nj].N = N; P.j[nj].K = K;
    P.j[nj].Kpad = Kpad; P.j[nj].rowofs = rowofs; P.j[nj].Nw = Nw; nj++;
  };
  add(enc_w1, W1B, 256, 115, 128, 0, 256);
  add(enc_w2, W2B, 128, 256, 256, 0, 128);
  add(proj_w, PWB, 128, 144, 160, 0, 128);
  for (int l = 0; l < NLD; l++)
    add(m_w_ig + (size_t)l*256*128, WIGB + (size_t)l*256*128, 256, 128, 128, 0, 256);
  for (int l = 0; l < NLD; l++){
    add(m_w_dt + (size_t)l*128*128, WDBCB + (size_t)l*144*128, 128, 128, 128, 0,   128);
    add(m_w_b  + (size_t)l*8*128,   WDBCB + (size_t)l*144*128,   8, 128, 128, 128,   8);
    add(m_w_c  + (size_t)l*8*128,   WDBCB + (size_t)l*144*128,   8, 128, 128, 136,   8);
  }
  for (int l = 0; l < NLD; l++)
    add(m_w_out + (size_t)l*128*128, WOUTB + (size_t)l*128*128, 128, 128, 128, 0, 128);
  add(pol_w1, PW1B, 128, 128, 128, 0, 128);
  add(pol_w2, PW2B,  19, 128, 128, 0,  32);

  k_prep<<<20*4, 256, 0, stream>>>(P);
  k_enc12p<<<NTOK/16, 256, 0, stream>>>(obs, W1B, enc_b1, enc_g1, enc_bb1,
      W2B, enc_b2, enc_g2, enc_bb2,
      emb, pact, PWB, proj_b, proj_g, proj_bb, X,
      m_ln_g, m_ln_b, WIGB, WDBCB, m_b_dt,
      XINb, Zb, DTb, BTu, CTu,
      m_a_log, HLA, PPA);

  const int scangrid = NTOK/16;   // 2048 blocks x 256 thr

  // layer 0 (carry computed in-block from HLA/PPA + h0)
  k_scan2p<<<scangrid, 256, 0, stream>>>(DTb, XINb, Zb, BTu, CTu,
      m_a_log, HLA, PPA, h0, m_d, WOUTB, X,
      m_ln_g + 128, m_ln_b + 128,
      WIGB + (size_t)256*128, WDBCB + (size_t)144*128, m_b_dt + 128,
      m_a_log + 1024, HLB, PPB);
  // layer 1
  k_scan2p<<<scangrid, 256, 0, stream>>>(DTb, XINb, Zb, BTu, CTu,
      m_a_log + 1024, HLB, PPB, h0 + (size_t)BB*1024, m_d + 128,
      WOUTB + (size_t)128*128, X,
      m_ln_g + 256, m_ln_b + 256,
      WIGB + (size_t)2*256*128, WDBCB + (size_t)2*144*128, m_b_dt + 256,
      m_a_log + 2048, HLA, PPA);
  // layer 2
  k_scan2h<<<scangrid, 256, 0, stream>>>(DTb, XINb, Zb, BTu, CTu,
      m_a_log + 2048, HLA, PPA, h0 + (size_t)2*BB*1024, m_d + 256,
      WOUTB + (size_t)2*128*128, X,
      fn_g, fn_b, PW1B, pol_b1, pol_g, pol_bb, PW2B, pol_b2,
      (float*)d_out);
}

// Round 10
// 402.669 us; speedup vs baseline: 1.0530x; 1.0530x over previous
//
#include <hip/hip_runtime.h>
#include <math.h>

#define BB 64
#define TT 512
#define OBSD 115
#define DMD 128
#define DSD 8
#define NLD 3
#define EMBD 16
#define NAD 19
#define H1D 256
#define NTOK (BB*TT)
#define SSEG 32
#define TSEG (TT/SSEG)   // 16

typedef unsigned short ushort_t;
typedef __attribute__((ext_vector_type(8))) short short8;
typedef __attribute__((ext_vector_type(4))) float f32x4;

__device__ __forceinline__ float silu_f(float x){ return x / (1.f + __expf(-x)); }
__device__ __forceinline__ float softplus_f(float x){
  return fmaxf(x, 0.f) + log1pf(__expf(-fabsf(x)));
}
__device__ __forceinline__ ushort_t f2bf(float x){
  unsigned u = __float_as_uint(x);
  unsigned r = (u + 0x7fffu + ((u >> 16) & 1u)) >> 16;
  return (ushort_t)r;
}
__device__ __forceinline__ float b2f(ushort_t x){
  return __uint_as_float(((unsigned)x) << 16);
}
#define MFMA(a,b,c) __builtin_amdgcn_mfma_f32_16x16x32_bf16((a),(b),(c),0,0,0)
#define LOG2E 1.44269504f

// ---------------- k_prep ----------------
struct PJob { const float* src; ushort_t* dst; int N; int K; int Kpad; int rowofs; int Nw; };
struct PJobs { PJob j[20]; };

__global__ __launch_bounds__(256) void k_prep(PJobs P){
  const int job = blockIdx.x >> 2;
  const int sub = blockIdx.x & 3;
  PJob pj = P.j[job];
  const int elems = pj.Nw * pj.Kpad;
  for (int idx = sub*256 + threadIdx.x; idx < elems; idx += 4*256){
    int n = idx / pj.Kpad;
    int k = idx - n*pj.Kpad;
    float v = (n < pj.N && k < pj.K) ? pj.src[(size_t)n*pj.K + k] : 0.f;
    pj.dst[(size_t)(pj.rowofs + n)*pj.Kpad + k] = f2bf(v);
  }
}

// ======== k_enc12p: enc1+enc2+proj+LN(l0)+wig/wdbc(l0)+phaseA(l0), 16 tok/block ========
// (256,8)@VGPR32 = 97us beats (256,6)@VGPR40 = 102us (r5 vs r8 A/B); conflicts identical.
__global__ __launch_bounds__(256, 8) void k_enc12p(
    const float* __restrict__ obs, const ushort_t* __restrict__ w1b,
    const float* __restrict__ b1, const float* __restrict__ g1,
    const float* __restrict__ bb1,
    const ushort_t* __restrict__ w2b,
    const float* __restrict__ b2, const float* __restrict__ g2,
    const float* __restrict__ bb2,
    const float* __restrict__ emb, const int* __restrict__ pact,
    const ushort_t* __restrict__ pwb, const float* __restrict__ pb,
    const float* __restrict__ pg, const float* __restrict__ pbb,
    float* __restrict__ X,
    const float* __restrict__ lng, const float* __restrict__ lnb,
    const ushort_t* __restrict__ wigb, const ushort_t* __restrict__ wdbcb,
    const float* __restrict__ bdt,
    ushort_t* __restrict__ XINb, ushort_t* __restrict__ Zb,
    ushort_t* __restrict__ DTb, ushort_t* __restrict__ BTu, ushort_t* __restrict__ CTu,
    const float* __restrict__ alog0,
    float* __restrict__ HLOC, float* __restrict__ PPR)
{
  __shared__ __align__(16) char sm[15104];
  ushort_t* s_obs = (ushort_t*)sm;
  ushort_t* s_e1  = (ushort_t*)sm;
  ushort_t* s_xin = (ushort_t*)sm;
  ushort_t* s_dt  = (ushort_t*)(sm + 4352);
  ushort_t* s_a2  = (ushort_t*)(sm + 8448);
  ushort_t* s_btc = (ushort_t*)(sm + 13824);
  float2*   s_st  = (float2*)(sm + 14080);
  float2*   s_st2 = (float2*)(sm + 14592);

  const int tok0 = blockIdx.x * 16;
  const int bidx = blockIdx.x >> 5;
  const int ch   = blockIdx.x & 31;
  const int tid = threadIdx.x;
  const int lane = tid & 63, w = tid >> 6;
  const int q = lane >> 4, cn = lane & 15;

  // -- P1: stage obs (pad 115->128) + emb --
  {
    const int t = tid >> 4, kc = tid & 15;
    const float* op = obs + (size_t)(tok0 + t)*OBSD;
    short8 v;
    #pragma unroll
    for (int j = 0; j < 8; j++){
      int k = kc*8 + j;
      v[j] = (short)f2bf(k < OBSD ? op[k] : 0.f);
    }
    *(short8*)&s_obs[t*136 + kc*8] = v;
  }
  for (int e = tid; e < 16*32; e += 256){
    int t = e >> 5, k = e & 31;
    float v = 0.f;
    if (k < EMBD){ int a = pact[tok0 + t]; v = emb[(size_t)a*EMBD + k]; }
    s_a2[t*168 + 128 + k] = f2bf(v);
  }
  __syncthreads();

  // -- P2: GEMM1 (N=256, 4 tiles/wave) -> acc regs; in-reg LN stats --
  f32x4 acc[4];
  {
    short8 af[4];
    #pragma unroll
    for (int ks = 0; ks < 4; ks++)
      af[ks] = *(const short8*)&s_obs[cn*136 + ks*32 + q*8];
    #pragma unroll
    for (int nt = 0; nt < 4; nt++){
      const int n0 = (w*4 + nt) * 16;
      f32x4 a = {0.f,0.f,0.f,0.f};
      #pragma unroll
      for (int ks = 0; ks < 4; ks++){
        short8 bf = *(const short8*)&w1b[(size_t)(n0 + cn)*128 + ks*32 + q*8];
        a = MFMA(af[ks], bf, a);
      }
      float bv = b1[n0 + cn];
      #pragma unroll
      for (int r = 0; r < 4; r++) a[r] += bv;
      acc[nt] = a;
    }
    #pragma unroll
    for (int r = 0; r < 4; r++){
      float s = 0.f, s2 = 0.f;
      #pragma unroll
      for (int nt = 0; nt < 4; nt++){ float v = acc[nt][r]; s += v; s2 = fmaf(v, v, s2); }
      s += __shfl_xor(s, 1, 64); s2 += __shfl_xor(s2, 1, 64);
      s += __shfl_xor(s, 2, 64); s2 += __shfl_xor(s2, 2, 64);
      s += __shfl_xor(s, 4, 64); s2 += __shfl_xor(s2, 4, 64);
      s += __shfl_xor(s, 8, 64); s2 += __shfl_xor(s2, 8, 64);
      if (cn == 0) s_st[(q*4 + r)*4 + w] = make_float2(s, s2);
    }
  }
  __syncthreads();   // s_obs dead

  // -- P3: normalize(256) + silu -> s_e1 --
  {
    float mu[4], rs[4];
    #pragma unroll
    for (int r = 0; r < 4; r++){
      const int row = q*4 + r;
      float2 p0 = s_st[row*4+0], p1 = s_st[row*4+1];
      float2 p2 = s_st[row*4+2], p3 = s_st[row*4+3];
      float s = p0.x+p1.x+p2.x+p3.x, s2 = p0.y+p1.y+p2.y+p3.y;
      float m = s * (1.f/256.f);
      mu[r] = m;
      rs[r] = rsqrtf(s2 * (1.f/256.f) - m*m + 1e-5f);
    }
    #pragma unroll
    for (int nt = 0; nt < 4; nt++){
      const int col = (w*4 + nt)*16 + cn;
      float gg = g1[col], bbv = bb1[col];
      #pragma unroll
      for (int r = 0; r < 4; r++){
        float v = (acc[nt][r] - mu[r]) * rs[r] * gg + bbv;
        s_e1[(q*4 + r)*264 + col] = f2bf(silu_f(v));
      }
    }
  }
  __syncthreads();

  // -- P4: GEMM2 (K=256, N=128, 2 tiles/wave) -> acc2; stats --
  f32x4 acc2[2];
  {
    short8 af2[8];
    #pragma unroll
    for (int ks = 0; ks < 8; ks++)
      af2[ks] = *(const short8*)&s_e1[cn*264 + ks*32 + q*8];
    #pragma unroll
    for (int nt = 0; nt < 2; nt++){
      const int n0 = (w*2 + nt) * 16;
      f32x4 a = {0.f,0.f,0.f,0.f};
      #pragma unroll
      for (int ks = 0; ks < 8; ks++){
        short8 bf = *(const short8*)&w2b[(size_t)(n0 + cn)*256 + ks*32 + q*8];
        a = MFMA(af2[ks], bf, a);
      }
      float bv = b2[n0 + cn];
      #pragma unroll
      for (int r = 0; r < 4; r++) a[r] += bv;
      acc2[nt] = a;
    }
    #pragma unroll
    for (int r = 0; r < 4; r++){
      float s = 0.f, s2 = 0.f;
      #pragma unroll
      for (int nt = 0; nt < 2; nt++){ float v = acc2[nt][r]; s += v; s2 = fmaf(v, v, s2); }
      s += __shfl_xor(s, 1, 64); s2 += __shfl_xor(s2, 1, 64);
      s += __shfl_xor(s, 2, 64); s2 += __shfl_xor(s2, 2, 64);
      s += __shfl_xor(s, 4, 64); s2 += __shfl_xor(s2, 4, 64);
      s += __shfl_xor(s, 8, 64); s2 += __shfl_xor(s2, 8, 64);
      if (cn == 0) s_st[(q*4 + r)*4 + w] = make_float2(s, s2);
    }
  }
  __syncthreads();

  // -- P5: normalize(g2/bb2) -> s_a2 cols [0,128) --
  {
    float mu[4], rs[4];
    #pragma unroll
    for (int r = 0; r < 4; r++){
      const int row = q*4 + r;
      float2 p0 = s_st[row*4+0], p1 = s_st[row*4+1];
      float2 p2 = s_st[row*4+2], p3 = s_st[row*4+3];
      float s = p0.x+p1.x+p2.x+p3.x, s2 = p0.y+p1.y+p2.y+p3.y;
      float m = s * (1.f/128.f);
      mu[r] = m;
      rs[r] = rsqrtf(s2 * (1.f/128.f) - m*m + 1e-5f);
    }
    #pragma unroll
    for (int nt = 0; nt < 2; nt++){
      const int col = (w*2 + nt)*16 + cn;
      float gg = g2[col], bbv = bb2[col];
      #pragma unroll
      for (int r = 0; r < 4; r++){
        float v = (acc2[nt][r] - mu[r]) * rs[r] * gg + bbv;
        s_a2[(q*4 + r)*168 + col] = f2bf(v);
      }
    }
  }
  __syncthreads();

  // -- P6: proj GEMM (K=160) -> acc3; stats --
  f32x4 acc3[2];
  {
    short8 af3[5];
    #pragma unroll
    for (int ks = 0; ks < 5; ks++)
      af3[ks] = *(const short8*)&s_a2[cn*168 + ks*32 + q*8];
    #pragma unroll
    for (int nt = 0; nt < 2; nt++){
      const int n0 = (w*2 + nt) * 16;
      f32x4 a = {0.f,0.f,0.f,0.f};
      #pragma unroll
      for (int ks = 0; ks < 5; ks++){
        short8 bf = *(const short8*)&pwb[(size_t)(n0 + cn)*160 + ks*32 + q*8];
        a = MFMA(af3[ks], bf, a);
      }
      float bv = pb[n0 + cn];
      #pragma unroll
      for (int r = 0; r < 4; r++) a[r] += bv;
      acc3[nt] = a;
    }
    #pragma unroll
    for (int r = 0; r < 4; r++){
      float s = 0.f, s2 = 0.f;
      #pragma unroll
      for (int nt = 0; nt < 2; nt++){ float v = acc3[nt][r]; s += v; s2 = fmaf(v, v, s2); }
      s += __shfl_xor(s, 1, 64); s2 += __shfl_xor(s2, 1, 64);
      s += __shfl_xor(s, 2, 64); s2 += __shfl_xor(s2, 2, 64);
      s += __shfl_xor(s, 4, 64); s2 += __shfl_xor(s2, 4, 64);
      s += __shfl_xor(s, 8, 64); s2 += __shfl_xor(s2, 8, 64);
      if (cn == 0) s_st[(q*4 + r)*4 + w] = make_float2(s, s2);
    }
  }
  __syncthreads();

  // -- P7: normalize(pg/pbb)+silu -> acc3 + X; stats2 --
  {
    float mu[4], rs[4];
    #pragma unroll
    for (int r = 0; r < 4; r++){
      const int row = q*4 + r;
      float2 p0 = s_st[row*4+0], p1 = s_st[row*4+1];
      float2 p2 = s_st[row*4+2], p3 = s_st[row*4+3];
      float s = p0.x+p1.x+p2.x+p3.x, s2 = p0.y+p1.y+p2.y+p3.y;
      float m = s * (1.f/128.f);
      mu[r] = m;
      rs[r] = rsqrtf(s2 * (1.f/128.f) - m*m + 1e-5f);
    }
    float ps[4] = {0.f,0.f,0.f,0.f}, ps2[4] = {0.f,0.f,0.f,0.f};
    #pragma unroll
    for (int nt = 0; nt < 2; nt++){
      const int col = (w*2 + nt)*16 + cn;
      float gg = pg[col], bbv = pbb[col];
      #pragma unroll
      for (int r = 0; r < 4; r++){
        float v = (acc3[nt][r] - mu[r]) * rs[r] * gg + bbv;
        v = silu_f(v);
        acc3[nt][r] = v;
        X[(size_t)(tok0 + q*4 + r)*128 + col] = v;
        ps[r] += v; ps2[r] = fmaf(v, v, ps2[r]);
      }
    }
    #pragma unroll
    for (int r = 0; r < 4; r++){
      float s = ps[r], s2 = ps2[r];
      s += __shfl_xor(s, 1, 64); s2 += __shfl_xor(s2, 1, 64);
      s += __shfl_xor(s, 2, 64); s2 += __shfl_xor(s2, 2, 64);
      s += __shfl_xor(s, 4, 64); s2 += __shfl_xor(s2, 4, 64);
      s += __shfl_xor(s, 8, 64); s2 += __shfl_xor(s2, 8, 64);
      if (cn == 0) s_st2[(q*4 + r)*4 + w] = make_float2(s, s2);
    }
  }
  __syncthreads();

  // -- P8: mamba LN (lng/lnb) -> s_a2 cols [0,128) --
  {
    float mu[4], rs[4];
    #pragma unroll
    for (int r = 0; r < 4; r++){
      const int row = q*4 + r;
      float2 p0 = s_st2[row*4+0], p1 = s_st2[row*4+1];
      float2 p2 = s_st2[row*4+2], p3 = s_st2[row*4+3];
      float s = p0.x+p1.x+p2.x+p3.x, s2 = p0.y+p1.y+p2.y+p3.y;
      float m = s * (1.f/128.f);
      mu[r] = m;
      rs[r] = rsqrtf(s2 * (1.f/128.f) - m*m + 1e-5f);
    }
    #pragma unroll
    for (int nt = 0; nt < 2; nt++){
      const int col = (w*2 + nt)*16 + cn;
      float gg = lng[col], bbv = lnb[col];
      #pragma unroll
      for (int r = 0; r < 4; r++){
        float v = (acc3[nt][r] - mu[r]) * rs[r] * gg + bbv;
        s_a2[(q*4 + r)*168 + col] = f2bf(v);
      }
    }
  }
  __syncthreads();

  // -- P9: wig GEMM (N=256, 4 tiles/wave) --
  {
    short8 af[4];
    #pragma unroll
    for (int ks = 0; ks < 4; ks++)
      af[ks] = *(const short8*)&s_a2[cn*168 + ks*32 + q*8];
    #pragma unroll
    for (int i = 0; i < 4; i++){
      const int n0 = (w*4 + i) * 16;
      f32x4 a = {0.f,0.f,0.f,0.f};
      #pragma unroll
      for (int ks = 0; ks < 4; ks++){
        short8 bf = *(const short8*)&wigb[(size_t)(n0 + cn)*128 + ks*32 + q*8];
        a = MFMA(af[ks], bf, a);
      }
      if (n0 < 128){
        #pragma unroll
        for (int r = 0; r < 4; r++){
          int tr = q*4 + r;
          ushort_t bb = f2bf(a[r]);
          XINb[(size_t)(tok0 + tr)*128 + n0 + cn] = bb;
          s_xin[tr*136 + n0 + cn] = bb;
        }
      } else {
        #pragma unroll
        for (int r = 0; r < 4; r++){
          int tr = q*4 + r;
          Zb[(size_t)(tok0 + tr)*128 + (n0 - 128) + cn] = f2bf(a[r]);
        }
      }
    }
  }
  __syncthreads();

  // -- P10: wdbc GEMM (N=144, nt=w..9 step 4) --
  {
    short8 af2[4];
    #pragma unroll
    for (int ks = 0; ks < 4; ks++)
      af2[ks] = *(const short8*)&s_xin[cn*136 + ks*32 + q*8];
    for (int nt = w; nt < 9; nt += 4){
      const int n0 = nt * 16;
      f32x4 a = {0.f,0.f,0.f,0.f};
      #pragma unroll
      for (int ks = 0; ks < 4; ks++){
        short8 bf = *(const short8*)&wdbcb[(size_t)(n0 + cn)*128 + ks*32 + q*8];
        a = MFMA(af2[ks], bf, a);
      }
      const int col = n0 + cn;
      if (col < 128){
        float bd = bdt[col];
        #pragma unroll
        for (int r = 0; r < 4; r++){
          int tr = q*4 + r;
          ushort_t dv = f2bf(softplus_f(a[r] + bd));
          DTb[(size_t)(tok0 + tr)*128 + col] = dv;
          s_dt[tr*136 + col] = dv;
        }
      } else if (col < 136){
        #pragma unroll
        for (int r = 0; r < 4; r++){
          int tr = q*4 + r;
          ushort_t bb = f2bf(a[r]);
          BTu[(size_t)(tok0 + tr)*8 + (col - 128)] = bb;
          s_btc[tr*8 + (col - 128)] = bb;
        }
      } else {
        #pragma unroll
        for (int r = 0; r < 4; r++)
          CTu[(size_t)(tok0 + q*4 + r)*8 + (col - 136)] = f2bf(a[r]);
      }
    }
  }
  __syncthreads();

  // -- P11: phase A (layer 0): thread=(d, s-half), 4 states, 16 tokens --
  {
    const int d = tid & 127, sh = tid >> 7;
    float A2c[4], hh[4], pp[4];
    #pragma unroll
    for (int j = 0; j < 4; j++){
      A2c[j] = -__expf(alog0[d*8 + sh*4 + j]) * LOG2E;
      hh[j] = 0.f; pp[j] = 1.f;
    }
    #pragma unroll 4
    for (int t = 0; t < 16; t++){
      float dt = b2f(s_dt[t*136 + d]);
      float wv = dt * b2f(s_xin[t*136 + d]);
      #pragma unroll
      for (int j = 0; j < 4; j++){
        float dA = exp2f(dt * A2c[j]);
        hh[j] = fmaf(dA, hh[j], wv * b2f(s_btc[t*8 + sh*4 + j]));
        pp[j] *= dA;
      }
    }
    const size_t o = ((size_t)bidx*SSEG + ch)*1024 + d*8 + sh*4;
    #pragma unroll
    for (int j = 0; j < 4; j++){ HLOC[o+j] = hh[j]; PPR[o+j] = pp[j]; }
  }
}

// ---- k_carry: HL[b,ch] := exclusive prefix (in place); prefetch-all then chain ----
__global__ __launch_bounds__(256) void k_carry(
    float* __restrict__ HL, const float* __restrict__ PP,
    const float* __restrict__ h0g)
{
  const int idx = blockIdx.x*256 + threadIdx.x;
  const size_t base = (size_t)(idx >> 10) * (SSEG*1024) + (idx & 1023);
  float hl[SSEG], pp[SSEG];
  #pragma unroll
  for (int ch = 0; ch < SSEG; ch++){
    hl[ch] = HL[base + (size_t)ch*1024];
    pp[ch] = PP[base + (size_t)ch*1024];
  }
  float h = h0g[idx];
  #pragma unroll
  for (int ch = 0; ch < SSEG; ch++){
    HL[base + (size_t)ch*1024] = h;
    h = fmaf(pp[ch], h, hl[ch]);
  }
}

// ======== phase B over 16 tokens: all-wave scan + wout + residual + in-reg LN stats ====
// X residual values prefetched at entry (T14): consumed only in the wout phase; no other
// block writes this block's X rows within this kernel, so the hoist is safe and hides
// the HBM/L2 latency under staging + scan.
// LDS (bytes):
//  [0,4096) s_dtS ; [4096,8192) s_xiS ; [8192,12288) s_zS   [dead after scan]
//  [0,8320)      s_x f32 16x130 (wout out; aliases staging)
//  [0,4352)      s_xin bf16 (wig out, late) ; [4352,8704) s_dt2 (wdbc out, late)
//  [12288,16640) s_a bf16 16x136
//  [16640,16896) s_bt ; [16896,17152) s_ct
//  [17152,17664) s_st float2[16][4]
#define SMB 17664

__device__ __forceinline__ void phaseB16(
    const ushort_t* DTb, const ushort_t* XINb, const ushort_t* Zb,
    const ushort_t* BTu, const ushort_t* CTu,
    const float* __restrict__ alog, const float* __restrict__ HLpre,
    const float* __restrict__ dpar, const ushort_t* __restrict__ woutb,
    float* __restrict__ X, char* sm, int b, int seg, int tid)
{
  ushort_t* s_dtS = (ushort_t*)sm;
  ushort_t* s_xiS = (ushort_t*)(sm + 4096);
  ushort_t* s_zS  = (ushort_t*)(sm + 8192);
  float*    s_x   = (float*)sm;
  ushort_t* s_a   = (ushort_t*)(sm + 12288);
  ushort_t* s_bt  = (ushort_t*)(sm + 16640);
  ushort_t* s_ct  = (ushort_t*)(sm + 16896);
  float2*   s_st  = (float2*)(sm + 17152);

  const int lane = tid & 63, w = tid >> 6, q = lane >> 4, cn = lane & 15;
  const size_t segtok = (size_t)b*TT + seg*TSEG;

  // T14: prefetch the 8 X residual values consumed in the wout phase
  float xpre[2][4];
  #pragma unroll
  for (int i = 0; i < 2; i++){
    const int n0 = (w*2 + i) * 16;
    #pragma unroll
    for (int r = 0; r < 4; r++)
      xpre[i][r] = X[(segtok + q*4 + r)*128 + n0 + cn];
  }

  // stage dt/xin/z (16x128 bf16 each = 256 uint4) + bt/ct
  ((uint4*)s_dtS)[tid] = ((const uint4*)(DTb  + segtok*128))[tid];
  ((uint4*)s_xiS)[tid] = ((const uint4*)(XINb + segtok*128))[tid];
  ((uint4*)s_zS )[tid] = ((const uint4*)(Zb   + segtok*128))[tid];
  if (tid < 64){
    ((unsigned*)s_bt)[tid] = ((const unsigned*)(BTu + segtok*8))[tid];
    ((unsigned*)s_ct)[tid] = ((const unsigned*)(CTu + segtok*8))[tid];
  }

  // recurrence state: all 256 threads; (d2, sh) = (w*32 + lane&31, lane>>5)
  const int d2 = (w << 5) | (lane & 31);
  const int sh = lane >> 5;
  float A2h[4], h[4];
  {
    const size_t o = ((size_t)b*SSEG + seg)*1024 + d2*8 + sh*4;
    float4 hv = *(const float4*)(HLpre + o);
    h[0]=hv.x; h[1]=hv.y; h[2]=hv.z; h[3]=hv.w;
    #pragma unroll
    for (int j = 0; j < 4; j++)
      A2h[j] = -__expf(alog[d2*8 + sh*4 + j]) * LOG2E;
  }
  const float dp = dpar[d2];
  __syncthreads();

  // scan: 4 states/thread; cross-half y combine via shfl_xor 32
  #pragma unroll 4
  for (int t = 0; t < 16; t++){
    float dt = b2f(s_dtS[t*128 + d2]);
    float xi = b2f(s_xiS[t*128 + d2]);
    float zv = b2f(s_zS [t*128 + d2]);
    float wv = dt * xi;
    float yp = 0.f;
    #pragma unroll
    for (int j = 0; j < 4; j++){
      float dA = exp2f(dt * A2h[j]);
      h[j] = fmaf(dA, h[j], wv * b2f(s_bt[t*8 + sh*4 + j]));
      yp = fmaf(h[j], b2f(s_ct[t*8 + sh*4 + j]), yp);
    }
    float y = yp + __shfl_xor(yp, 32, 64);
    float ssm = y * silu_f(zv) + xi * dp;
    if (sh == 0) s_a[t*136 + d2] = f2bf(ssm);
  }
  __syncthreads();   // staging dead; s_x writable

  // wout GEMM (N=128, 2 tiles/wave) + residual (prefetched) -> s_x + X; in-reg LN stats
  {
    short8 af[4];
    #pragma unroll
    for (int ks = 0; ks < 4; ks++)
      af[ks] = *(const short8*)&s_a[cn*136 + ks*32 + q*8];
    float ps[4] = {0.f,0.f,0.f,0.f}, ps2[4] = {0.f,0.f,0.f,0.f};
    #pragma unroll
    for (int i = 0; i < 2; i++){
      const int n0 = (w*2 + i) * 16;
      short8 bf[4];
      #pragma unroll
      for (int ks = 0; ks < 4; ks++)
        bf[ks] = *(const short8*)&woutb[(size_t)(n0+cn)*128 + ks*32 + q*8];
      f32x4 acc = {0.f,0.f,0.f,0.f};
      #pragma unroll
      for (int ks = 0; ks < 4; ks++) acc = MFMA(af[ks], bf[ks], acc);
      #pragma unroll
      for (int r = 0; r < 4; r++){
        const int tr = q*4 + r;
        const size_t g = (segtok + tr)*128 + n0 + cn;
        float xn = xpre[i][r] + acc[r];
        X[g] = xn;
        s_x[tr*130 + n0 + cn] = xn;
        ps[r] += xn; ps2[r] = fmaf(xn, xn, ps2[r]);
      }
    }
    #pragma unroll
    for (int r = 0; r < 4; r++){
      float s = ps[r], s2 = ps2[r];
      s += __shfl_xor(s, 1, 64); s2 += __shfl_xor(s2, 1, 64);
      s += __shfl_xor(s, 2, 64); s2 += __shfl_xor(s2, 2, 64);
      s += __shfl_xor(s, 4, 64); s2 += __shfl_xor(s2, 4, 64);
      s += __shfl_xor(s, 8, 64); s2 += __shfl_xor(s2, 8, 64);
      if (cn == 0) s_st[(q*4 + r)*4 + w] = make_float2(s, s2);
    }
  }
  __syncthreads();
}

// ---- k_scan2p: 16-token block; phaseB, LN, wig, wdbc, phaseA(next) ----
__global__ __launch_bounds__(256, 6) void k_scan2p(
    ushort_t* DTb, ushort_t* XINb, ushort_t* Zb,
    ushort_t* BTu, ushort_t* CTu,
    const float* __restrict__ alog, const float* __restrict__ HLpre,
    const float* __restrict__ dpar, const ushort_t* __restrict__ woutb,
    float* __restrict__ X,
    const float* __restrict__ lng, const float* __restrict__ lnb,
    const ushort_t* __restrict__ wigb, const ushort_t* __restrict__ wdbcb,
    const float* __restrict__ bdt,
    const float* __restrict__ alogn,
    float* __restrict__ HLo, float* __restrict__ PPo)
{
  __shared__ __align__(16) char sm[SMB];
  const int tid = threadIdx.x;
  float*    s_x   = (float*)sm;
  ushort_t* s_xin = (ushort_t*)sm;
  ushort_t* s_dt2 = (ushort_t*)(sm + 4352);
  ushort_t* s_a   = (ushort_t*)(sm + 12288);
  ushort_t* s_btc = (ushort_t*)(sm + 16640);
  float2*   s_st  = (float2*)(sm + 17152);

  const int b = blockIdx.x >> 5;
  const int seg = blockIdx.x & 31;
  const int lane = tid & 63, w = tid >> 6, q = lane >> 4, cn = lane & 15;
  const size_t segtok = (size_t)b*TT + seg*TSEG;

  phaseB16(DTb, XINb, Zb, BTu, CTu, alog, HLpre, dpar, woutb, X, sm, b, seg, tid);

  // P4: normalize (lng/lnb) -> s_a
  {
    const int d = tid & 127, half = tid >> 7;
    float g = lng[d], c0v = lnb[d];
    #pragma unroll
    for (int tt = 0; tt < 8; tt++){
      const int t = half*8 + tt;
      float2 p0 = s_st[t*4+0], p1 = s_st[t*4+1];
      float2 p2 = s_st[t*4+2], p3 = s_st[t*4+3];
      float ssum = p0.x+p1.x+p2.x+p3.x, ss2 = p0.y+p1.y+p2.y+p3.y;
      float mu = ssum * (1.f/128.f);
      float rs = rsqrtf(ss2 * (1.f/128.f) - mu*mu + 1e-5f);
      float v = (s_x[t*130 + d] - mu) * rs * g + c0v;
      s_a[t*136 + d] = f2bf(v);
    }
  }
  __syncthreads();

  // P5: wig GEMM (N=256, 4 tiles/wave); writes s_xin (aliases dead s_x) + XINb/Zb
  {
    short8 af[4];
    #pragma unroll
    for (int ks = 0; ks < 4; ks++)
      af[ks] = *(const short8*)&s_a[cn*136 + ks*32 + q*8];
    #pragma unroll
    for (int i = 0; i < 4; i++){
      const int n0 = (w*4 + i) * 16;
      short8 bf[4];
      #pragma unroll
      for (int ks = 0; ks < 4; ks++)
        bf[ks] = *(const short8*)&wigb[(size_t)(n0+cn)*128 + ks*32 + q*8];
      f32x4 acc = {0.f,0.f,0.f,0.f};
      #pragma unroll
      for (int ks = 0; ks < 4; ks++) acc = MFMA(af[ks], bf[ks], acc);
      if (n0 < 128){
        #pragma unroll
        for (int r = 0; r < 4; r++){
          const int tr = q*4 + r;
          ushort_t bb = f2bf(acc[r]);
          XINb[(segtok + tr)*128 + n0 + cn] = bb;
          s_xin[tr*136 + n0 + cn] = bb;
        }
      } else {
        #pragma unroll
        for (int r = 0; r < 4; r++){
          const int tr = q*4 + r;
          Zb[(segtok + tr)*128 + (n0-128) + cn] = f2bf(acc[r]);
        }
      }
    }
  }
  __syncthreads();

  // P6: wdbc GEMM; fills s_dt2 / s_btc
  {
    short8 af2[4];
    #pragma unroll
    for (int ks = 0; ks < 4; ks++)
      af2[ks] = *(const short8*)&s_xin[cn*136 + ks*32 + q*8];
    for (int nt = w; nt < 9; nt += 4){
      const int n0 = nt * 16;
      short8 bf[4];
      #pragma unroll
      for (int ks = 0; ks < 4; ks++)
        bf[ks] = *(const short8*)&wdbcb[(size_t)(n0+cn)*128 + ks*32 + q*8];
      f32x4 acc = {0.f,0.f,0.f,0.f};
      #pragma unroll
      for (int ks = 0; ks < 4; ks++) acc = MFMA(af2[ks], bf[ks], acc);
      const int col = n0 + cn;
      if (col < 128){
        float bd = bdt[col];
        #pragma unroll
        for (int r = 0; r < 4; r++){
          const int tr = q*4 + r;
          ushort_t dv = f2bf(softplus_f(acc[r] + bd));
          DTb[(segtok + tr)*128 + col] = dv;
          s_dt2[tr*136 + col] = dv;
        }
      } else if (col < 136){
        #pragma unroll
        for (int r = 0; r < 4; r++){
          const int tr = q*4 + r;
          ushort_t bb = f2bf(acc[r]);
          BTu[(segtok + tr)*8 + (col-128)] = bb;
          s_btc[tr*8 + (col-128)] = bb;
        }
      } else {
        #pragma unroll
        for (int r = 0; r < 4; r++)
          CTu[(segtok + q*4 + r)*8 + (col-136)] = f2bf(acc[r]);
      }
    }
  }
  __syncthreads();

  // P7: phase A (next layer): thread=(d, s-half), 4 states, 16 tokens
  {
    const int d = tid & 127, sh = tid >> 7;
    float A2n[4], hh[4], pp[4];
    #pragma unroll
    for (int j = 0; j < 4; j++){
      A2n[j] = -__expf(alogn[d*8 + sh*4 + j]) * LOG2E;
      hh[j] = 0.f; pp[j] = 1.f;
    }
    #pragma unroll 4
    for (int t = 0; t < 16; t++){
      float dt = b2f(s_dt2[t*136 + d]);
      float wv = dt * b2f(s_xin[t*136 + d]);
      #pragma unroll
      for (int j = 0; j < 4; j++){
        float dA = exp2f(dt * A2n[j]);
        hh[j] = fmaf(dA, hh[j], wv * b2f(s_btc[t*8 + sh*4 + j]));
        pp[j] *= dA;
      }
    }
    const size_t o = ((size_t)b*SSEG + seg)*1024 + d*8 + sh*4;
    #pragma unroll
    for (int j = 0; j < 4; j++){ HLo[o+j] = hh[j]; PPo[o+j] = pp[j]; }
  }
}

// ---- k_scan2h: 16-token block; phaseB, LNfn, pw1(+stats), LN+silu, pw2 ----
__global__ __launch_bounds__(256, 6) void k_scan2h(
    const ushort_t* DTb, const ushort_t* XINb, const ushort_t* Zb,
    const ushort_t* BTu, const ushort_t* CTu,
    const float* __restrict__ alog, const float* __restrict__ HLpre,
    const float* __restrict__ dpar, const ushort_t* __restrict__ woutb,
    float* __restrict__ X,
    const float* __restrict__ fng, const float* __restrict__ fnb,
    const ushort_t* __restrict__ pw1b, const float* __restrict__ pb1,
    const float* __restrict__ pg, const float* __restrict__ pbb,
    const ushort_t* __restrict__ pw2b, const float* __restrict__ pb2,
    float* __restrict__ out)
{
  __shared__ __align__(16) char sm[SMB];
  const int tid = threadIdx.x;
  float*    s_x  = (float*)sm;
  ushort_t* s_a  = (ushort_t*)(sm + 12288);
  float2*   s_st = (float2*)(sm + 17152);

  const int b = blockIdx.x >> 5;
  const int seg = blockIdx.x & 31;
  const int lane = tid & 63, w = tid >> 6, q = lane >> 4, cn = lane & 15;
  const size_t segtok = (size_t)b*TT + seg*TSEG;

  phaseB16((ushort_t*)DTb, (ushort_t*)XINb, (ushort_t*)Zb,
           (ushort_t*)BTu, (ushort_t*)CTu, alog, HLpre,
           dpar, woutb, X, sm, b, seg, tid);

  // P4: LN_fn -> s_a
  {
    const int d = tid & 127, half = tid >> 7;
    float g = fng[d], c0v = fnb[d];
    #pragma unroll
    for (int tt = 0; tt < 8; tt++){
      const int t = half*8 + tt;
      float2 p0 = s_st[t*4+0], p1 = s_st[t*4+1];
      float2 p2 = s_st[t*4+2], p3 = s_st[t*4+3];
      float ssum = p0.x+p1.x+p2.x+p3.x, ss2 = p0.y+p1.y+p2.y+p3.y;
      float mu = ssum * (1.f/128.f);
      float rs = rsqrtf(ss2 * (1.f/128.f) - mu*mu + 1e-5f);
      float v = (s_x[t*130 + d] - mu) * rs * g + c0v;
      s_a[t*136 + d] = f2bf(v);
    }
  }
  __syncthreads();

  // P5: pw1 GEMM (N=128, 2 tiles/wave) -> s_x (+bias); in-reg stats
  {
    short8 af[4];
    #pragma unroll
    for (int ks = 0; ks < 4; ks++)
      af[ks] = *(const short8*)&s_a[cn*136 + ks*32 + q*8];
    float ps[4] = {0.f,0.f,0.f,0.f}, ps2[4] = {0.f,0.f,0.f,0.f};
    #pragma unroll
    for (int i = 0; i < 2; i++){
      const int n0 = (w*2 + i) * 16;
      short8 bf[4];
      #pragma unroll
      for (int ks = 0; ks < 4; ks++)
        bf[ks] = *(const short8*)&pw1b[(size_t)(n0+cn)*128 + ks*32 + q*8];
      float bias = pb1[n0 + cn];
      f32x4 acc = {0.f,0.f,0.f,0.f};
      #pragma unroll
      for (int ks = 0; ks < 4; ks++) acc = MFMA(af[ks], bf[ks], acc);
      #pragma unroll
      for (int r = 0; r < 4; r++){
        float xv = acc[r] + bias;
        s_x[(q*4 + r)*130 + n0 + cn] = xv;
        ps[r] += xv; ps2[r] = fmaf(xv, xv, ps2[r]);
      }
    }
    #pragma unroll
    for (int r = 0; r < 4; r++){
      float s = ps[r], s2 = ps2[r];
      s += __shfl_xor(s, 1, 64); s2 += __shfl_xor(s2, 1, 64);
      s += __shfl_xor(s, 2, 64); s2 += __shfl_xor(s2, 2, 64);
      s += __shfl_xor(s, 4, 64); s2 += __shfl_xor(s2, 4, 64);
      s += __shfl_xor(s, 8, 64); s2 += __shfl_xor(s2, 8, 64);
      if (cn == 0) s_st[(q*4 + r)*4 + w] = make_float2(s, s2);
    }
  }
  __syncthreads();

  // P6: LN(pg/pbb)+silu -> s_a
  {
    const int d = tid & 127, half = tid >> 7;
    float g = pg[d], c0v = pbb[d];
    #pragma unroll
    for (int tt = 0; tt < 8; tt++){
      const int t = half*8 + tt;
      float2 p0 = s_st[t*4+0], p1 = s_st[t*4+1];
      float2 p2 = s_st[t*4+2], p3 = s_st[t*4+3];
      float ssum = p0.x+p1.x+p2.x+p3.x, ss2 = p0.y+p1.y+p2.y+p3.y;
      float mu = ssum * (1.f/128.f);
      float rs = rsqrtf(ss2 * (1.f/128.f) - mu*mu + 1e-5f);
      float v = (s_x[t*130 + d] - mu) * rs * g + c0v;
      s_a[t*136 + d] = f2bf(silu_f(v));
    }
  }
  __syncthreads();

  // P7: pw2 GEMM (N=32; waves 0,1; cols<19 stored)
  if (w < 2){
    short8 af[4];
    #pragma unroll
    for (int ks = 0; ks < 4; ks++)
      af[ks] = *(const short8*)&s_a[cn*136 + ks*32 + q*8];
    const int n0 = w * 16;
    short8 bf[4];
    #pragma unroll
    for (int ks = 0; ks < 4; ks++)
      bf[ks] = *(const short8*)&pw2b[(size_t)(n0+cn)*128 + ks*32 + q*8];
    const int col = n0 + cn;
    f32x4 acc = {0.f,0.f,0.f,0.f};
    #pragma unroll
    for (int ks = 0; ks < 4; ks++) acc = MFMA(af[ks], bf[ks], acc);
    if (col < NAD){
      float bias = pb2[col];
      #pragma unroll
      for (int r = 0; r < 4; r++)
        out[(segtok + q*4 + r)*NAD + col] = acc[r] + bias;
    }
  }
}

extern "C" void kernel_launch(void* const* d_in, const int* in_sizes, int n_in,
                              void* d_out, int out_size, void* d_ws, size_t ws_size,
                              hipStream_t stream) {
  const float* obs    = (const float*)d_in[0];
  const float* h0     = (const float*)d_in[1];
  const float* enc_w1 = (const float*)d_in[2];
  const float* enc_b1 = (const float*)d_in[3];
  const float* enc_g1 = (const float*)d_in[4];
  const float* enc_bb1= (const float*)d_in[5];
  const float* enc_w2 = (const float*)d_in[6];
  const float* enc_b2 = (const float*)d_in[7];
  const float* enc_g2 = (const float*)d_in[8];
  const float* enc_bb2= (const float*)d_in[9];
  const float* emb    = (const float*)d_in[10];
  const float* proj_w = (const float*)d_in[11];
  const float* proj_b = (const float*)d_in[12];
  const float* proj_g = (const float*)d_in[13];
  const float* proj_bb= (const float*)d_in[14];
  const float* m_ln_g = (const float*)d_in[15];
  const float* m_ln_b = (const float*)d_in[16];
  const float* m_w_ig = (const float*)d_in[17];
  const float* m_w_dt = (const float*)d_in[18];
  const float* m_b_dt = (const float*)d_in[19];
  const float* m_a_log= (const float*)d_in[20];
  const float* m_w_b  = (const float*)d_in[21];
  const float* m_w_c  = (const float*)d_in[22];
  const float* m_d    = (const float*)d_in[23];
  const float* m_w_out= (const float*)d_in[24];
  const float* fn_g   = (const float*)d_in[25];
  const float* fn_b   = (const float*)d_in[26];
  const float* pol_w1 = (const float*)d_in[27];
  const float* pol_b1 = (const float*)d_in[28];
  const float* pol_g  = (const float*)d_in[29];
  const float* pol_bb = (const float*)d_in[30];
  const float* pol_w2 = (const float*)d_in[31];
  const float* pol_b2 = (const float*)d_in[32];
  const int*   pact   = (const int*)d_in[33];

  float* ws  = (float*)d_ws;
  float* X    = ws;
  float* HLA  = X + (size_t)NTOK*128;
  float* PPA  = HLA + (size_t)BB*SSEG*1024;
  float* HLB  = PPA + (size_t)BB*SSEG*1024;
  float* PPB  = HLB + (size_t)BB*SSEG*1024;
  ushort_t* XINb = (ushort_t*)(PPB + (size_t)BB*SSEG*1024);
  ushort_t* Zb   = XINb + (size_t)NTOK*128;
  ushort_t* DTb  = Zb   + (size_t)NTOK*128;
  ushort_t* BTu  = DTb  + (size_t)NTOK*128;
  ushort_t* CTu  = BTu  + (size_t)NTOK*8;

  ushort_t* W1B   = CTu   + (size_t)NTOK*8;
  ushort_t* W2B   = W1B   + 256*128;
  ushort_t* PWB   = W2B   + 128*256;
  ushort_t* WIGB  = PWB   + 128*160;
  ushort_t* WDBCB = WIGB  + 3*256*128;
  ushort_t* WOUTB = WDBCB + 3*144*128;
  ushort_t* PW1B  = WOUTB + 3*128*128;
  ushort_t* PW2B  = PW1B  + 128*128;

  PJobs P;
  int nj = 0;
  auto add = [&](const float* src, ushort_t* dst, int N, int K, int Kpad, int rowofs, int Nw){
    P.j[nj].src = src; P.j[nj].dst = dst; P.j[nj].N = N; P.j[nj].K = K;
    P.j[nj].Kpad = Kpad; P.j[nj].rowofs = rowofs; P.j[nj].Nw = Nw; nj++;
  };
  add(enc_w1, W1B, 256, 115, 128, 0, 256);
  add(enc_w2, W2B, 128, 256, 256, 0, 128);
  add(proj_w, PWB, 128, 144, 160, 0, 128);
  for (int l = 0; l < NLD; l++)
    add(m_w_ig + (size_t)l*256*128, WIGB + (size_t)l*256*128, 256, 128, 128, 0, 256);
  for (int l = 0; l < NLD; l++){
    add(m_w_dt + (size_t)l*128*128, WDBCB + (size_t)l*144*128, 128, 128, 128, 0,   128);
    add(m_w_b  + (size_t)l*8*128,   WDBCB + (size_t)l*144*128,   8, 128, 128, 128,   8);
    add(m_w_c  + (size_t)l*8*128,   WDBCB + (size_t)l*144*128,   8, 128, 128, 136,   8);
  }
  for (int l = 0; l < NLD; l++)
    add(m_w_out + (size_t)l*128*128, WOUTB + (size_t)l*128*128, 128, 128, 128, 0, 128);
  add(pol_w1, PW1B, 128, 128, 128, 0, 128);
  add(pol_w2, PW2B,  19, 128, 128, 0,  32);

  k_prep<<<20*4, 256, 0, stream>>>(P);
  k_enc12p<<<NTOK/16, 256, 0, stream>>>(obs, W1B, enc_b1, enc_g1, enc_bb1,
      W2B, enc_b2, enc_g2, enc_bb2,
      emb, pact, PWB, proj_b, proj_g, proj_bb, X,
      m_ln_g, m_ln_b, WIGB, WDBCB, m_b_dt,
      XINb, Zb, DTb, BTu, CTu,
      m_a_log, HLA, PPA);

  const int carrygrid = BB*1024/256;   // 256 blocks
  const int scangrid  = NTOK/16;       // 2048 blocks x 256 thr

  // layer 0
  k_carry<<<carrygrid, 256, 0, stream>>>(HLA, PPA, h0);
  k_scan2p<<<scangrid, 256, 0, stream>>>(DTb, XINb, Zb, BTu, CTu,
      m_a_log, HLA, m_d, WOUTB, X,
      m_ln_g + 128, m_ln_b + 128,
      WIGB + (size_t)256*128, WDBCB + (size_t)144*128, m_b_dt + 128,
      m_a_log + 1024, HLB, PPB);
  // layer 1
  k_carry<<<carrygrid, 256, 0, stream>>>(HLB, PPB, h0 + (size_t)BB*1024);
  k_scan2p<<<scangrid, 256, 0, stream>>>(DTb, XINb, Zb, BTu, CTu,
      m_a_log + 1024, HLB, m_d + 128, WOUTB + (size_t)128*128, X,
      m_ln_g + 256, m_ln_b + 256,
      WIGB + (size_t)2*256*128, WDBCB + (size_t)2*144*128, m_b_dt + 256,
      m_a_log + 2048, HLA, PPA);
  // layer 2
  k_carry<<<carrygrid, 256, 0, stream>>>(HLA, PPA, h0 + (size_t)2*BB*1024);
  k_scan2h<<<scangrid, 256, 0, stream>>>(DTb, XINb, Zb, BTu, CTu,
      m_a_log + 2048, HLA, m_d + 256, WOUTB + (size_t)2*128*128, X,
      fn_g, fn_b, PW1B, pol_b1, pol_g, pol_bb, PW2B, pol_b2,
      (float*)d_out);
}

// Round 11
// 402.003 us; speedup vs baseline: 1.0547x; 1.0017x over previous
//
#include <hip/hip_runtime.h>
#include <math.h>

#define BB 64
#define TT 512
#define OBSD 115
#define DMD 128
#define DSD 8
#define NLD 3
#define EMBD 16
#define NAD 19
#define H1D 256
#define NTOK (BB*TT)
#define SSEG 32
#define TSEG (TT/SSEG)   // 16

typedef unsigned short ushort_t;
typedef __attribute__((ext_vector_type(8))) short short8;
typedef __attribute__((ext_vector_type(4))) float f32x4;

__device__ __forceinline__ float silu_f(float x){ return x / (1.f + __expf(-x)); }
__device__ __forceinline__ float softplus_f(float x){
  return fmaxf(x, 0.f) + log1pf(__expf(-fabsf(x)));
}
__device__ __forceinline__ ushort_t f2bf(float x){
  unsigned u = __float_as_uint(x);
  unsigned r = (u + 0x7fffu + ((u >> 16) & 1u)) >> 16;
  return (ushort_t)r;
}
__device__ __forceinline__ float b2f(ushort_t x){
  return __uint_as_float(((unsigned)x) << 16);
}
#define MFMA(a,b,c) __builtin_amdgcn_mfma_f32_16x16x32_bf16((a),(b),(c),0,0,0)
#define LOG2E 1.44269504f

// ---------------- k_prep ----------------
struct PJob { const float* src; ushort_t* dst; int N; int K; int Kpad; int rowofs; int Nw; };
struct PJobs { PJob j[20]; };

__global__ __launch_bounds__(256) void k_prep(PJobs P){
  const int job = blockIdx.x >> 2;
  const int sub = blockIdx.x & 3;
  PJob pj = P.j[job];
  const int elems = pj.Nw * pj.Kpad;
  for (int idx = sub*256 + threadIdx.x; idx < elems; idx += 4*256){
    int n = idx / pj.Kpad;
    int k = idx - n*pj.Kpad;
    float v = (n < pj.N && k < pj.K) ? pj.src[(size_t)n*pj.K + k] : 0.f;
    pj.dst[(size_t)(pj.rowofs + n)*pj.Kpad + k] = f2bf(v);
  }
}

// ======== k_enc12p: enc1+enc2+proj+LN(l0)+wig/wdbc(l0)+phaseA(l0), 16 tok/block ========
// (256,8)@VGPR32 = 97us beats (256,6)@VGPR40 = 102us (r5 vs r8 A/B); conflicts identical.
__global__ __launch_bounds__(256, 8) void k_enc12p(
    const float* __restrict__ obs, const ushort_t* __restrict__ w1b,
    const float* __restrict__ b1, const float* __restrict__ g1,
    const float* __restrict__ bb1,
    const ushort_t* __restrict__ w2b,
    const float* __restrict__ b2, const float* __restrict__ g2,
    const float* __restrict__ bb2,
    const float* __restrict__ emb, const int* __restrict__ pact,
    const ushort_t* __restrict__ pwb, const float* __restrict__ pb,
    const float* __restrict__ pg, const float* __restrict__ pbb,
    float* __restrict__ X,
    const float* __restrict__ lng, const float* __restrict__ lnb,
    const ushort_t* __restrict__ wigb, const ushort_t* __restrict__ wdbcb,
    const float* __restrict__ bdt,
    ushort_t* __restrict__ XINb, ushort_t* __restrict__ Zb,
    ushort_t* __restrict__ DTb, ushort_t* __restrict__ BTu, ushort_t* __restrict__ CTu,
    const float* __restrict__ alog0,
    float* __restrict__ HLOC, float* __restrict__ PPR)
{
  __shared__ __align__(16) char sm[15104];
  ushort_t* s_obs = (ushort_t*)sm;
  ushort_t* s_e1  = (ushort_t*)sm;
  ushort_t* s_xin = (ushort_t*)sm;
  ushort_t* s_dt  = (ushort_t*)(sm + 4352);
  ushort_t* s_a2  = (ushort_t*)(sm + 8448);
  ushort_t* s_btc = (ushort_t*)(sm + 13824);
  float2*   s_st  = (float2*)(sm + 14080);
  float2*   s_st2 = (float2*)(sm + 14592);

  const int tok0 = blockIdx.x * 16;
  const int bidx = blockIdx.x >> 5;
  const int ch   = blockIdx.x & 31;
  const int tid = threadIdx.x;
  const int lane = tid & 63, w = tid >> 6;
  const int q = lane >> 4, cn = lane & 15;

  // -- P1: stage obs (pad 115->128) + emb --
  {
    const int t = tid >> 4, kc = tid & 15;
    const float* op = obs + (size_t)(tok0 + t)*OBSD;
    short8 v;
    #pragma unroll
    for (int j = 0; j < 8; j++){
      int k = kc*8 + j;
      v[j] = (short)f2bf(k < OBSD ? op[k] : 0.f);
    }
    *(short8*)&s_obs[t*136 + kc*8] = v;
  }
  for (int e = tid; e < 16*32; e += 256){
    int t = e >> 5, k = e & 31;
    float v = 0.f;
    if (k < EMBD){ int a = pact[tok0 + t]; v = emb[(size_t)a*EMBD + k]; }
    s_a2[t*168 + 128 + k] = f2bf(v);
  }
  __syncthreads();

  // -- P2: GEMM1 (N=256, 4 tiles/wave) -> acc regs; in-reg LN stats --
  f32x4 acc[4];
  {
    short8 af[4];
    #pragma unroll
    for (int ks = 0; ks < 4; ks++)
      af[ks] = *(const short8*)&s_obs[cn*136 + ks*32 + q*8];
    #pragma unroll
    for (int nt = 0; nt < 4; nt++){
      const int n0 = (w*4 + nt) * 16;
      f32x4 a = {0.f,0.f,0.f,0.f};
      #pragma unroll
      for (int ks = 0; ks < 4; ks++){
        short8 bf = *(const short8*)&w1b[(size_t)(n0 + cn)*128 + ks*32 + q*8];
        a = MFMA(af[ks], bf, a);
      }
      float bv = b1[n0 + cn];
      #pragma unroll
      for (int r = 0; r < 4; r++) a[r] += bv;
      acc[nt] = a;
    }
    #pragma unroll
    for (int r = 0; r < 4; r++){
      float s = 0.f, s2 = 0.f;
      #pragma unroll
      for (int nt = 0; nt < 4; nt++){ float v = acc[nt][r]; s += v; s2 = fmaf(v, v, s2); }
      s += __shfl_xor(s, 1, 64); s2 += __shfl_xor(s2, 1, 64);
      s += __shfl_xor(s, 2, 64); s2 += __shfl_xor(s2, 2, 64);
      s += __shfl_xor(s, 4, 64); s2 += __shfl_xor(s2, 4, 64);
      s += __shfl_xor(s, 8, 64); s2 += __shfl_xor(s2, 8, 64);
      if (cn == 0) s_st[(q*4 + r)*4 + w] = make_float2(s, s2);
    }
  }
  __syncthreads();   // s_obs dead

  // -- P3: normalize(256) + silu -> s_e1 --
  {
    float mu[4], rs[4];
    #pragma unroll
    for (int r = 0; r < 4; r++){
      const int row = q*4 + r;
      float2 p0 = s_st[row*4+0], p1 = s_st[row*4+1];
      float2 p2 = s_st[row*4+2], p3 = s_st[row*4+3];
      float s = p0.x+p1.x+p2.x+p3.x, s2 = p0.y+p1.y+p2.y+p3.y;
      float m = s * (1.f/256.f);
      mu[r] = m;
      rs[r] = rsqrtf(s2 * (1.f/256.f) - m*m + 1e-5f);
    }
    #pragma unroll
    for (int nt = 0; nt < 4; nt++){
      const int col = (w*4 + nt)*16 + cn;
      float gg = g1[col], bbv = bb1[col];
      #pragma unroll
      for (int r = 0; r < 4; r++){
        float v = (acc[nt][r] - mu[r]) * rs[r] * gg + bbv;
        s_e1[(q*4 + r)*264 + col] = f2bf(silu_f(v));
      }
    }
  }
  __syncthreads();

  // -- P4: GEMM2 (K=256, N=128, 2 tiles/wave) -> acc2; stats --
  f32x4 acc2[2];
  {
    short8 af2[8];
    #pragma unroll
    for (int ks = 0; ks < 8; ks++)
      af2[ks] = *(const short8*)&s_e1[cn*264 + ks*32 + q*8];
    #pragma unroll
    for (int nt = 0; nt < 2; nt++){
      const int n0 = (w*2 + nt) * 16;
      f32x4 a = {0.f,0.f,0.f,0.f};
      #pragma unroll
      for (int ks = 0; ks < 8; ks++){
        short8 bf = *(const short8*)&w2b[(size_t)(n0 + cn)*256 + ks*32 + q*8];
        a = MFMA(af2[ks], bf, a);
      }
      float bv = b2[n0 + cn];
      #pragma unroll
      for (int r = 0; r < 4; r++) a[r] += bv;
      acc2[nt] = a;
    }
    #pragma unroll
    for (int r = 0; r < 4; r++){
      float s = 0.f, s2 = 0.f;
      #pragma unroll
      for (int nt = 0; nt < 2; nt++){ float v = acc2[nt][r]; s += v; s2 = fmaf(v, v, s2); }
      s += __shfl_xor(s, 1, 64); s2 += __shfl_xor(s2, 1, 64);
      s += __shfl_xor(s, 2, 64); s2 += __shfl_xor(s2, 2, 64);
      s += __shfl_xor(s, 4, 64); s2 += __shfl_xor(s2, 4, 64);
      s += __shfl_xor(s, 8, 64); s2 += __shfl_xor(s2, 8, 64);
      if (cn == 0) s_st[(q*4 + r)*4 + w] = make_float2(s, s2);
    }
  }
  __syncthreads();

  // -- P5: normalize(g2/bb2) -> s_a2 cols [0,128) --
  {
    float mu[4], rs[4];
    #pragma unroll
    for (int r = 0; r < 4; r++){
      const int row = q*4 + r;
      float2 p0 = s_st[row*4+0], p1 = s_st[row*4+1];
      float2 p2 = s_st[row*4+2], p3 = s_st[row*4+3];
      float s = p0.x+p1.x+p2.x+p3.x, s2 = p0.y+p1.y+p2.y+p3.y;
      float m = s * (1.f/128.f);
      mu[r] = m;
      rs[r] = rsqrtf(s2 * (1.f/128.f) - m*m + 1e-5f);
    }
    #pragma unroll
    for (int nt = 0; nt < 2; nt++){
      const int col = (w*2 + nt)*16 + cn;
      float gg = g2[col], bbv = bb2[col];
      #pragma unroll
      for (int r = 0; r < 4; r++){
        float v = (acc2[nt][r] - mu[r]) * rs[r] * gg + bbv;
        s_a2[(q*4 + r)*168 + col] = f2bf(v);
      }
    }
  }
  __syncthreads();

  // -- P6: proj GEMM (K=160) -> acc3; stats --
  f32x4 acc3[2];
  {
    short8 af3[5];
    #pragma unroll
    for (int ks = 0; ks < 5; ks++)
      af3[ks] = *(const short8*)&s_a2[cn*168 + ks*32 + q*8];
    #pragma unroll
    for (int nt = 0; nt < 2; nt++){
      const int n0 = (w*2 + nt) * 16;
      f32x4 a = {0.f,0.f,0.f,0.f};
      #pragma unroll
      for (int ks = 0; ks < 5; ks++){
        short8 bf = *(const short8*)&pwb[(size_t)(n0 + cn)*160 + ks*32 + q*8];
        a = MFMA(af3[ks], bf, a);
      }
      float bv = pb[n0 + cn];
      #pragma unroll
      for (int r = 0; r < 4; r++) a[r] += bv;
      acc3[nt] = a;
    }
    #pragma unroll
    for (int r = 0; r < 4; r++){
      float s = 0.f, s2 = 0.f;
      #pragma unroll
      for (int nt = 0; nt < 2; nt++){ float v = acc3[nt][r]; s += v; s2 = fmaf(v, v, s2); }
      s += __shfl_xor(s, 1, 64); s2 += __shfl_xor(s2, 1, 64);
      s += __shfl_xor(s, 2, 64); s2 += __shfl_xor(s2, 2, 64);
      s += __shfl_xor(s, 4, 64); s2 += __shfl_xor(s2, 4, 64);
      s += __shfl_xor(s, 8, 64); s2 += __shfl_xor(s2, 8, 64);
      if (cn == 0) s_st[(q*4 + r)*4 + w] = make_float2(s, s2);
    }
  }
  __syncthreads();

  // -- P7: normalize(pg/pbb)+silu -> acc3 + X; stats2 --
  {
    float mu[4], rs[4];
    #pragma unroll
    for (int r = 0; r < 4; r++){
      const int row = q*4 + r;
      float2 p0 = s_st[row*4+0], p1 = s_st[row*4+1];
      float2 p2 = s_st[row*4+2], p3 = s_st[row*4+3];
      float s = p0.x+p1.x+p2.x+p3.x, s2 = p0.y+p1.y+p2.y+p3.y;
      float m = s * (1.f/128.f);
      mu[r] = m;
      rs[r] = rsqrtf(s2 * (1.f/128.f) - m*m + 1e-5f);
    }
    float ps[4] = {0.f,0.f,0.f,0.f}, ps2[4] = {0.f,0.f,0.f,0.f};
    #pragma unroll
    for (int nt = 0; nt < 2; nt++){
      const int col = (w*2 + nt)*16 + cn;
      float gg = pg[col], bbv = pbb[col];
      #pragma unroll
      for (int r = 0; r < 4; r++){
        float v = (acc3[nt][r] - mu[r]) * rs[r] * gg + bbv;
        v = silu_f(v);
        acc3[nt][r] = v;
        X[(size_t)(tok0 + q*4 + r)*128 + col] = v;
        ps[r] += v; ps2[r] = fmaf(v, v, ps2[r]);
      }
    }
    #pragma unroll
    for (int r = 0; r < 4; r++){
      float s = ps[r], s2 = ps2[r];
      s += __shfl_xor(s, 1, 64); s2 += __shfl_xor(s2, 1, 64);
      s += __shfl_xor(s, 2, 64); s2 += __shfl_xor(s2, 2, 64);
      s += __shfl_xor(s, 4, 64); s2 += __shfl_xor(s2, 4, 64);
      s += __shfl_xor(s, 8, 64); s2 += __shfl_xor(s2, 8, 64);
      if (cn == 0) s_st2[(q*4 + r)*4 + w] = make_float2(s, s2);
    }
  }
  __syncthreads();

  // -- P8: mamba LN (lng/lnb) -> s_a2 cols [0,128) --
  {
    float mu[4], rs[4];
    #pragma unroll
    for (int r = 0; r < 4; r++){
      const int row = q*4 + r;
      float2 p0 = s_st2[row*4+0], p1 = s_st2[row*4+1];
      float2 p2 = s_st2[row*4+2], p3 = s_st2[row*4+3];
      float s = p0.x+p1.x+p2.x+p3.x, s2 = p0.y+p1.y+p2.y+p3.y;
      float m = s * (1.f/128.f);
      mu[r] = m;
      rs[r] = rsqrtf(s2 * (1.f/128.f) - m*m + 1e-5f);
    }
    #pragma unroll
    for (int nt = 0; nt < 2; nt++){
      const int col = (w*2 + nt)*16 + cn;
      float gg = lng[col], bbv = lnb[col];
      #pragma unroll
      for (int r = 0; r < 4; r++){
        float v = (acc3[nt][r] - mu[r]) * rs[r] * gg + bbv;
        s_a2[(q*4 + r)*168 + col] = f2bf(v);
      }
    }
  }
  __syncthreads();

  // -- P9: wig GEMM (N=256, 4 tiles/wave) --
  {
    short8 af[4];
    #pragma unroll
    for (int ks = 0; ks < 4; ks++)
      af[ks] = *(const short8*)&s_a2[cn*168 + ks*32 + q*8];
    #pragma unroll
    for (int i = 0; i < 4; i++){
      const int n0 = (w*4 + i) * 16;
      f32x4 a = {0.f,0.f,0.f,0.f};
      #pragma unroll
      for (int ks = 0; ks < 4; ks++){
        short8 bf = *(const short8*)&wigb[(size_t)(n0 + cn)*128 + ks*32 + q*8];
        a = MFMA(af[ks], bf, a);
      }
      if (n0 < 128){
        #pragma unroll
        for (int r = 0; r < 4; r++){
          int tr = q*4 + r;
          ushort_t bb = f2bf(a[r]);
          XINb[(size_t)(tok0 + tr)*128 + n0 + cn] = bb;
          s_xin[tr*136 + n0 + cn] = bb;
        }
      } else {
        #pragma unroll
        for (int r = 0; r < 4; r++){
          int tr = q*4 + r;
          Zb[(size_t)(tok0 + tr)*128 + (n0 - 128) + cn] = f2bf(a[r]);
        }
      }
    }
  }
  __syncthreads();

  // -- P10: wdbc GEMM (N=144, nt=w..9 step 4) --
  {
    short8 af2[4];
    #pragma unroll
    for (int ks = 0; ks < 4; ks++)
      af2[ks] = *(const short8*)&s_xin[cn*136 + ks*32 + q*8];
    for (int nt = w; nt < 9; nt += 4){
      const int n0 = nt * 16;
      f32x4 a = {0.f,0.f,0.f,0.f};
      #pragma unroll
      for (int ks = 0; ks < 4; ks++){
        short8 bf = *(const short8*)&wdbcb[(size_t)(n0 + cn)*128 + ks*32 + q*8];
        a = MFMA(af2[ks], bf, a);
      }
      const int col = n0 + cn;
      if (col < 128){
        float bd = bdt[col];
        #pragma unroll
        for (int r = 0; r < 4; r++){
          int tr = q*4 + r;
          ushort_t dv = f2bf(softplus_f(a[r] + bd));
          DTb[(size_t)(tok0 + tr)*128 + col] = dv;
          s_dt[tr*136 + col] = dv;
        }
      } else if (col < 136){
        #pragma unroll
        for (int r = 0; r < 4; r++){
          int tr = q*4 + r;
          ushort_t bb = f2bf(a[r]);
          BTu[(size_t)(tok0 + tr)*8 + (col - 128)] = bb;
          s_btc[tr*8 + (col - 128)] = bb;
        }
      } else {
        #pragma unroll
        for (int r = 0; r < 4; r++)
          CTu[(size_t)(tok0 + q*4 + r)*8 + (col - 136)] = f2bf(a[r]);
      }
    }
  }
  __syncthreads();

  // -- P11: phase A (layer 0): thread=(d, s-half), 4 states, 16 tokens --
  {
    const int d = tid & 127, sh = tid >> 7;
    float A2c[4], hh[4], pp[4];
    #pragma unroll
    for (int j = 0; j < 4; j++){
      A2c[j] = -__expf(alog0[d*8 + sh*4 + j]) * LOG2E;
      hh[j] = 0.f; pp[j] = 1.f;
    }
    #pragma unroll 4
    for (int t = 0; t < 16; t++){
      float dt = b2f(s_dt[t*136 + d]);
      float wv = dt * b2f(s_xin[t*136 + d]);
      #pragma unroll
      for (int j = 0; j < 4; j++){
        float dA = exp2f(dt * A2c[j]);
        hh[j] = fmaf(dA, hh[j], wv * b2f(s_btc[t*8 + sh*4 + j]));
        pp[j] *= dA;
      }
    }
    const size_t o = ((size_t)bidx*SSEG + ch)*1024 + d*8 + sh*4;
    #pragma unroll
    for (int j = 0; j < 4; j++){ HLOC[o+j] = hh[j]; PPR[o+j] = pp[j]; }
  }
}

// ---- k_carry: two-level exclusive prefix; 64 elems/block, 4 sub-ranges of 8 chunks ----
// Thread (e, sub): composes its 8 chunk-maps (h -> P h + H), publishes (P,H) to LDS,
// applies the <=3 preceding sub-maps to h0, rewrites its 8 chunks with the running prefix.
// 1024 blocks x 256 thr = 16 waves/CU (vs 4 for the flat version); chain 32 -> 19 steps.
__global__ __launch_bounds__(256) void k_carry(
    float* __restrict__ HL, const float* __restrict__ PP,
    const float* __restrict__ h0g)
{
  __shared__ float s_P[3*64], s_H[3*64];
  const int e   = threadIdx.x & 63;
  const int sub = threadIdx.x >> 6;
  const int idx = blockIdx.x*64 + e;
  const size_t base = (size_t)(idx >> 10) * (SSEG*1024) + (idx & 1023);
  const int c0 = sub*8;

  float hl[8], pp[8];
  #pragma unroll
  for (int c = 0; c < 8; c++){
    hl[c] = HL[base + (size_t)(c0+c)*1024];
    pp[c] = PP[base + (size_t)(c0+c)*1024];
  }
  // compose own range: map h -> Pc*h + Hc
  float Pc = 1.f, Hc = 0.f;
  #pragma unroll
  for (int c = 0; c < 8; c++){
    Hc = fmaf(pp[c], Hc, hl[c]);
    Pc *= pp[c];
  }
  if (sub < 3){ s_P[sub*64 + e] = Pc; s_H[sub*64 + e] = Hc; }
  float h = h0g[idx];
  __syncthreads();
  #pragma unroll
  for (int s = 0; s < 3; s++){
    if (s < sub) h = fmaf(s_P[s*64 + e], h, s_H[s*64 + e]);
  }
  #pragma unroll
  for (int c = 0; c < 8; c++){
    HL[base + (size_t)(c0+c)*1024] = h;
    h = fmaf(pp[c], h, hl[c]);
  }
}

// ======== phase B over 16 tokens: all-wave scan + wout + residual + in-reg LN stats ====
// LDS (bytes):
//  [0,4096) s_dtS ; [4096,8192) s_xiS ; [8192,12288) s_zS   [dead after scan]
//  [0,8320)      s_x f32 16x130 (wout out; aliases staging)
//  [0,4352)      s_xin bf16 (wig out, late) ; [4352,8704) s_dt2 (wdbc out, late)
//  [12288,16640) s_a bf16 16x136
//  [16640,16896) s_bt ; [16896,17152) s_ct
//  [17152,17664) s_st float2[16][4]
#define SMB 17664

__device__ __forceinline__ void phaseB16(
    const ushort_t* DTb, const ushort_t* XINb, const ushort_t* Zb,
    const ushort_t* BTu, const ushort_t* CTu,
    const float* __restrict__ alog, const float* __restrict__ HLpre,
    const float* __restrict__ dpar, const ushort_t* __restrict__ woutb,
    float* __restrict__ X, char* sm, int b, int seg, int tid)
{
  ushort_t* s_dtS = (ushort_t*)sm;
  ushort_t* s_xiS = (ushort_t*)(sm + 4096);
  ushort_t* s_zS  = (ushort_t*)(sm + 8192);
  float*    s_x   = (float*)sm;
  ushort_t* s_a   = (ushort_t*)(sm + 12288);
  ushort_t* s_bt  = (ushort_t*)(sm + 16640);
  ushort_t* s_ct  = (ushort_t*)(sm + 16896);
  float2*   s_st  = (float2*)(sm + 17152);

  const int lane = tid & 63, w = tid >> 6, q = lane >> 4, cn = lane & 15;
  const size_t segtok = (size_t)b*TT + seg*TSEG;

  // T14: prefetch the 8 X residual values consumed in the wout phase
  float xpre[2][4];
  #pragma unroll
  for (int i = 0; i < 2; i++){
    const int n0 = (w*2 + i) * 16;
    #pragma unroll
    for (int r = 0; r < 4; r++)
      xpre[i][r] = X[(segtok + q*4 + r)*128 + n0 + cn];
  }

  // stage dt/xin/z (16x128 bf16 each = 256 uint4) + bt/ct
  ((uint4*)s_dtS)[tid] = ((const uint4*)(DTb  + segtok*128))[tid];
  ((uint4*)s_xiS)[tid] = ((const uint4*)(XINb + segtok*128))[tid];
  ((uint4*)s_zS )[tid] = ((const uint4*)(Zb   + segtok*128))[tid];
  if (tid < 64){
    ((unsigned*)s_bt)[tid] = ((const unsigned*)(BTu + segtok*8))[tid];
    ((unsigned*)s_ct)[tid] = ((const unsigned*)(CTu + segtok*8))[tid];
  }

  // recurrence state: all 256 threads; (d2, sh) = (w*32 + lane&31, lane>>5)
  const int d2 = (w << 5) | (lane & 31);
  const int sh = lane >> 5;
  float A2h[4], h[4];
  {
    const size_t o = ((size_t)b*SSEG + seg)*1024 + d2*8 + sh*4;
    float4 hv = *(const float4*)(HLpre + o);
    h[0]=hv.x; h[1]=hv.y; h[2]=hv.z; h[3]=hv.w;
    #pragma unroll
    for (int j = 0; j < 4; j++)
      A2h[j] = -__expf(alog[d2*8 + sh*4 + j]) * LOG2E;
  }
  const float dp = dpar[d2];
  __syncthreads();

  // scan: 4 states/thread; cross-half y combine via shfl_xor 32
  #pragma unroll 4
  for (int t = 0; t < 16; t++){
    float dt = b2f(s_dtS[t*128 + d2]);
    float xi = b2f(s_xiS[t*128 + d2]);
    float zv = b2f(s_zS [t*128 + d2]);
    float wv = dt * xi;
    float yp = 0.f;
    #pragma unroll
    for (int j = 0; j < 4; j++){
      float dA = exp2f(dt * A2h[j]);
      h[j] = fmaf(dA, h[j], wv * b2f(s_bt[t*8 + sh*4 + j]));
      yp = fmaf(h[j], b2f(s_ct[t*8 + sh*4 + j]), yp);
    }
    float y = yp + __shfl_xor(yp, 32, 64);
    float ssm = y * silu_f(zv) + xi * dp;
    if (sh == 0) s_a[t*136 + d2] = f2bf(ssm);
  }
  __syncthreads();   // staging dead; s_x writable

  // wout GEMM (N=128, 2 tiles/wave) + residual (prefetched) -> s_x + X; in-reg LN stats
  {
    short8 af[4];
    #pragma unroll
    for (int ks = 0; ks < 4; ks++)
      af[ks] = *(const short8*)&s_a[cn*136 + ks*32 + q*8];
    float ps[4] = {0.f,0.f,0.f,0.f}, ps2[4] = {0.f,0.f,0.f,0.f};
    #pragma unroll
    for (int i = 0; i < 2; i++){
      const int n0 = (w*2 + i) * 16;
      short8 bf[4];
      #pragma unroll
      for (int ks = 0; ks < 4; ks++)
        bf[ks] = *(const short8*)&woutb[(size_t)(n0+cn)*128 + ks*32 + q*8];
      f32x4 acc = {0.f,0.f,0.f,0.f};
      #pragma unroll
      for (int ks = 0; ks < 4; ks++) acc = MFMA(af[ks], bf[ks], acc);
      #pragma unroll
      for (int r = 0; r < 4; r++){
        const int tr = q*4 + r;
        const size_t g = (segtok + tr)*128 + n0 + cn;
        float xn = xpre[i][r] + acc[r];
        X[g] = xn;
        s_x[tr*130 + n0 + cn] = xn;
        ps[r] += xn; ps2[r] = fmaf(xn, xn, ps2[r]);
      }
    }
    #pragma unroll
    for (int r = 0; r < 4; r++){
      float s = ps[r], s2 = ps2[r];
      s += __shfl_xor(s, 1, 64); s2 += __shfl_xor(s2, 1, 64);
      s += __shfl_xor(s, 2, 64); s2 += __shfl_xor(s2, 2, 64);
      s += __shfl_xor(s, 4, 64); s2 += __shfl_xor(s2, 4, 64);
      s += __shfl_xor(s, 8, 64); s2 += __shfl_xor(s2, 8, 64);
      if (cn == 0) s_st[(q*4 + r)*4 + w] = make_float2(s, s2);
    }
  }
  __syncthreads();
}

// ---- k_scan2p: 16-token block; phaseB, LN, wig, wdbc, phaseA(next) ----
__global__ __launch_bounds__(256, 6) void k_scan2p(
    ushort_t* DTb, ushort_t* XINb, ushort_t* Zb,
    ushort_t* BTu, ushort_t* CTu,
    const float* __restrict__ alog, const float* __restrict__ HLpre,
    const float* __restrict__ dpar, const ushort_t* __restrict__ woutb,
    float* __restrict__ X,
    const float* __restrict__ lng, const float* __restrict__ lnb,
    const ushort_t* __restrict__ wigb, const ushort_t* __restrict__ wdbcb,
    const float* __restrict__ bdt,
    const float* __restrict__ alogn,
    float* __restrict__ HLo, float* __restrict__ PPo)
{
  __shared__ __align__(16) char sm[SMB];
  const int tid = threadIdx.x;
  float*    s_x   = (float*)sm;
  ushort_t* s_xin = (ushort_t*)sm;
  ushort_t* s_dt2 = (ushort_t*)(sm + 4352);
  ushort_t* s_a   = (ushort_t*)(sm + 12288);
  ushort_t* s_btc = (ushort_t*)(sm + 16640);
  float2*   s_st  = (float2*)(sm + 17152);

  const int b = blockIdx.x >> 5;
  const int seg = blockIdx.x & 31;
  const int lane = tid & 63, w = tid >> 6, q = lane >> 4, cn = lane & 15;
  const size_t segtok = (size_t)b*TT + seg*TSEG;

  phaseB16(DTb, XINb, Zb, BTu, CTu, alog, HLpre, dpar, woutb, X, sm, b, seg, tid);

  // P4: normalize (lng/lnb) -> s_a
  {
    const int d = tid & 127, half = tid >> 7;
    float g = lng[d], c0v = lnb[d];
    #pragma unroll
    for (int tt = 0; tt < 8; tt++){
      const int t = half*8 + tt;
      float2 p0 = s_st[t*4+0], p1 = s_st[t*4+1];
      float2 p2 = s_st[t*4+2], p3 = s_st[t*4+3];
      float ssum = p0.x+p1.x+p2.x+p3.x, ss2 = p0.y+p1.y+p2.y+p3.y;
      float mu = ssum * (1.f/128.f);
      float rs = rsqrtf(ss2 * (1.f/128.f) - mu*mu + 1e-5f);
      float v = (s_x[t*130 + d] - mu) * rs * g + c0v;
      s_a[t*136 + d] = f2bf(v);
    }
  }
  __syncthreads();

  // P5: wig GEMM (N=256, 4 tiles/wave); writes s_xin (aliases dead s_x) + XINb/Zb
  {
    short8 af[4];
    #pragma unroll
    for (int ks = 0; ks < 4; ks++)
      af[ks] = *(const short8*)&s_a[cn*136 + ks*32 + q*8];
    #pragma unroll
    for (int i = 0; i < 4; i++){
      const int n0 = (w*4 + i) * 16;
      short8 bf[4];
      #pragma unroll
      for (int ks = 0; ks < 4; ks++)
        bf[ks] = *(const short8*)&wigb[(size_t)(n0+cn)*128 + ks*32 + q*8];
      f32x4 acc = {0.f,0.f,0.f,0.f};
      #pragma unroll
      for (int ks = 0; ks < 4; ks++) acc = MFMA(af[ks], bf[ks], acc);
      if (n0 < 128){
        #pragma unroll
        for (int r = 0; r < 4; r++){
          const int tr = q*4 + r;
          ushort_t bb = f2bf(acc[r]);
          XINb[(segtok + tr)*128 + n0 + cn] = bb;
          s_xin[tr*136 + n0 + cn] = bb;
        }
      } else {
        #pragma unroll
        for (int r = 0; r < 4; r++){
          const int tr = q*4 + r;
          Zb[(segtok + tr)*128 + (n0-128) + cn] = f2bf(acc[r]);
        }
      }
    }
  }
  __syncthreads();

  // P6: wdbc GEMM; fills s_dt2 / s_btc
  {
    short8 af2[4];
    #pragma unroll
    for (int ks = 0; ks < 4; ks++)
      af2[ks] = *(const short8*)&s_xin[cn*136 + ks*32 + q*8];
    for (int nt = w; nt < 9; nt += 4){
      const int n0 = nt * 16;
      short8 bf[4];
      #pragma unroll
      for (int ks = 0; ks < 4; ks++)
        bf[ks] = *(const short8*)&wdbcb[(size_t)(n0+cn)*128 + ks*32 + q*8];
      f32x4 acc = {0.f,0.f,0.f,0.f};
      #pragma unroll
      for (int ks = 0; ks < 4; ks++) acc = MFMA(af2[ks], bf[ks], acc);
      const int col = n0 + cn;
      if (col < 128){
        float bd = bdt[col];
        #pragma unroll
        for (int r = 0; r < 4; r++){
          const int tr = q*4 + r;
          ushort_t dv = f2bf(softplus_f(acc[r] + bd));
          DTb[(segtok + tr)*128 + col] = dv;
          s_dt2[tr*136 + col] = dv;
        }
      } else if (col < 136){
        #pragma unroll
        for (int r = 0; r < 4; r++){
          const int tr = q*4 + r;
          ushort_t bb = f2bf(acc[r]);
          BTu[(segtok + tr)*8 + (col-128)] = bb;
          s_btc[tr*8 + (col-128)] = bb;
        }
      } else {
        #pragma unroll
        for (int r = 0; r < 4; r++)
          CTu[(segtok + q*4 + r)*8 + (col-136)] = f2bf(acc[r]);
      }
    }
  }
  __syncthreads();

  // P7: phase A (next layer): thread=(d, s-half), 4 states, 16 tokens
  {
    const int d = tid & 127, sh = tid >> 7;
    float A2n[4], hh[4], pp[4];
    #pragma unroll
    for (int j = 0; j < 4; j++){
      A2n[j] = -__expf(alogn[d*8 + sh*4 + j]) * LOG2E;
      hh[j] = 0.f; pp[j] = 1.f;
    }
    #pragma unroll 4
    for (int t = 0; t < 16; t++){
      float dt = b2f(s_dt2[t*136 + d]);
      float wv = dt * b2f(s_xin[t*136 + d]);
      #pragma unroll
      for (int j = 0; j < 4; j++){
        float dA = exp2f(dt * A2n[j]);
        hh[j] = fmaf(dA, hh[j], wv * b2f(s_btc[t*8 + sh*4 + j]));
        pp[j] *= dA;
      }
    }
    const size_t o = ((size_t)b*SSEG + seg)*1024 + d*8 + sh*4;
    #pragma unroll
    for (int j = 0; j < 4; j++){ HLo[o+j] = hh[j]; PPo[o+j] = pp[j]; }
  }
}

// ---- k_scan2h: 16-token block; phaseB, LNfn, pw1(+stats), LN+silu, pw2 ----
__global__ __launch_bounds__(256, 6) void k_scan2h(
    const ushort_t* DTb, const ushort_t* XINb, const ushort_t* Zb,
    const ushort_t* BTu, const ushort_t* CTu,
    const float* __restrict__ alog, const float* __restrict__ HLpre,
    const float* __restrict__ dpar, const ushort_t* __restrict__ woutb,
    float* __restrict__ X,
    const float* __restrict__ fng, const float* __restrict__ fnb,
    const ushort_t* __restrict__ pw1b, const float* __restrict__ pb1,
    const float* __restrict__ pg, const float* __restrict__ pbb,
    const ushort_t* __restrict__ pw2b, const float* __restrict__ pb2,
    float* __restrict__ out)
{
  __shared__ __align__(16) char sm[SMB];
  const int tid = threadIdx.x;
  float*    s_x  = (float*)sm;
  ushort_t* s_a  = (ushort_t*)(sm + 12288);
  float2*   s_st = (float2*)(sm + 17152);

  const int b = blockIdx.x >> 5;
  const int seg = blockIdx.x & 31;
  const int lane = tid & 63, w = tid >> 6, q = lane >> 4, cn = lane & 15;
  const size_t segtok = (size_t)b*TT + seg*TSEG;

  phaseB16((ushort_t*)DTb, (ushort_t*)XINb, (ushort_t*)Zb,
           (ushort_t*)BTu, (ushort_t*)CTu, alog, HLpre,
           dpar, woutb, X, sm, b, seg, tid);

  // P4: LN_fn -> s_a
  {
    const int d = tid & 127, half = tid >> 7;
    float g = fng[d], c0v = fnb[d];
    #pragma unroll
    for (int tt = 0; tt < 8; tt++){
      const int t = half*8 + tt;
      float2 p0 = s_st[t*4+0], p1 = s_st[t*4+1];
      float2 p2 = s_st[t*4+2], p3 = s_st[t*4+3];
      float ssum = p0.x+p1.x+p2.x+p3.x, ss2 = p0.y+p1.y+p2.y+p3.y;
      float mu = ssum * (1.f/128.f);
      float rs = rsqrtf(ss2 * (1.f/128.f) - mu*mu + 1e-5f);
      float v = (s_x[t*130 + d] - mu) * rs * g + c0v;
      s_a[t*136 + d] = f2bf(v);
    }
  }
  __syncthreads();

  // P5: pw1 GEMM (N=128, 2 tiles/wave) -> s_x (+bias); in-reg stats
  {
    short8 af[4];
    #pragma unroll
    for (int ks = 0; ks < 4; ks++)
      af[ks] = *(const short8*)&s_a[cn*136 + ks*32 + q*8];
    float ps[4] = {0.f,0.f,0.f,0.f}, ps2[4] = {0.f,0.f,0.f,0.f};
    #pragma unroll
    for (int i = 0; i < 2; i++){
      const int n0 = (w*2 + i) * 16;
      short8 bf[4];
      #pragma unroll
      for (int ks = 0; ks < 4; ks++)
        bf[ks] = *(const short8*)&pw1b[(size_t)(n0+cn)*128 + ks*32 + q*8];
      float bias = pb1[n0 + cn];
      f32x4 acc = {0.f,0.f,0.f,0.f};
      #pragma unroll
      for (int ks = 0; ks < 4; ks++) acc = MFMA(af[ks], bf[ks], acc);
      #pragma unroll
      for (int r = 0; r < 4; r++){
        float xv = acc[r] + bias;
        s_x[(q*4 + r)*130 + n0 + cn] = xv;
        ps[r] += xv; ps2[r] = fmaf(xv, xv, ps2[r]);
      }
    }
    #pragma unroll
    for (int r = 0; r < 4; r++){
      float s = ps[r], s2 = ps2[r];
      s += __shfl_xor(s, 1, 64); s2 += __shfl_xor(s2, 1, 64);
      s += __shfl_xor(s, 2, 64); s2 += __shfl_xor(s2, 2, 64);
      s += __shfl_xor(s, 4, 64); s2 += __shfl_xor(s2, 4, 64);
      s += __shfl_xor(s, 8, 64); s2 += __shfl_xor(s2, 8, 64);
      if (cn == 0) s_st[(q*4 + r)*4 + w] = make_float2(s, s2);
    }
  }
  __syncthreads();

  // P6: LN(pg/pbb)+silu -> s_a
  {
    const int d = tid & 127, half = tid >> 7;
    float g = pg[d], c0v = pbb[d];
    #pragma unroll
    for (int tt = 0; tt < 8; tt++){
      const int t = half*8 + tt;
      float2 p0 = s_st[t*4+0], p1 = s_st[t*4+1];
      float2 p2 = s_st[t*4+2], p3 = s_st[t*4+3];
      float ssum = p0.x+p1.x+p2.x+p3.x, ss2 = p0.y+p1.y+p2.y+p3.y;
      float mu = ssum * (1.f/128.f);
      float rs = rsqrtf(ss2 * (1.f/128.f) - mu*mu + 1e-5f);
      float v = (s_x[t*130 + d] - mu) * rs * g + c0v;
      s_a[t*136 + d] = f2bf(silu_f(v));
    }
  }
  __syncthreads();

  // P7: pw2 GEMM (N=32; waves 0,1; cols<19 stored)
  if (w < 2){
    short8 af[4];
    #pragma unroll
    for (int ks = 0; ks < 4; ks++)
      af[ks] = *(const short8*)&s_a[cn*136 + ks*32 + q*8];
    const int n0 = w * 16;
    short8 bf[4];
    #pragma unroll
    for (int ks = 0; ks < 4; ks++)
      bf[ks] = *(const short8*)&pw2b[(size_t)(n0+cn)*128 + ks*32 + q*8];
    const int col = n0 + cn;
    f32x4 acc = {0.f,0.f,0.f,0.f};
    #pragma unroll
    for (int ks = 0; ks < 4; ks++) acc = MFMA(af[ks], bf[ks], acc);
    if (col < NAD){
      float bias = pb2[col];
      #pragma unroll
      for (int r = 0; r < 4; r++)
        out[(segtok + q*4 + r)*NAD + col] = acc[r] + bias;
    }
  }
}

extern "C" void kernel_launch(void* const* d_in, const int* in_sizes, int n_in,
                              void* d_out, int out_size, void* d_ws, size_t ws_size,
                              hipStream_t stream) {
  const float* obs    = (const float*)d_in[0];
  const float* h0     = (const float*)d_in[1];
  const float* enc_w1 = (const float*)d_in[2];
  const float* enc_b1 = (const float*)d_in[3];
  const float* enc_g1 = (const float*)d_in[4];
  const float* enc_bb1= (const float*)d_in[5];
  const float* enc_w2 = (const float*)d_in[6];
  const float* enc_b2 = (const float*)d_in[7];
  const float* enc_g2 = (const float*)d_in[8];
  const float* enc_bb2= (const float*)d_in[9];
  const float* emb    = (const float*)d_in[10];
  const float* proj_w = (const float*)d_in[11];
  const float* proj_b = (const float*)d_in[12];
  const float* proj_g = (const float*)d_in[13];
  const float* proj_bb= (const float*)d_in[14];
  const float* m_ln_g = (const float*)d_in[15];
  const float* m_ln_b = (const float*)d_in[16];
  const float* m_w_ig = (const float*)d_in[17];
  const float* m_w_dt = (const float*)d_in[18];
  const float* m_b_dt = (const float*)d_in[19];
  const float* m_a_log= (const float*)d_in[20];
  const float* m_w_b  = (const float*)d_in[21];
  const float* m_w_c  = (const float*)d_in[22];
  const float* m_d    = (const float*)d_in[23];
  const float* m_w_out= (const float*)d_in[24];
  const float* fn_g   = (const float*)d_in[25];
  const float* fn_b   = (const float*)d_in[26];
  const float* pol_w1 = (const float*)d_in[27];
  const float* pol_b1 = (const float*)d_in[28];
  const float* pol_g  = (const float*)d_in[29];
  const float* pol_bb = (const float*)d_in[30];
  const float* pol_w2 = (const float*)d_in[31];
  const float* pol_b2 = (const float*)d_in[32];
  const int*   pact   = (const int*)d_in[33];

  float* ws  = (float*)d_ws;
  float* X    = ws;
  float* HLA  = X + (size_t)NTOK*128;
  float* PPA  = HLA + (size_t)BB*SSEG*1024;
  float* HLB  = PPA + (size_t)BB*SSEG*1024;
  float* PPB  = HLB + (size_t)BB*SSEG*1024;
  ushort_t* XINb = (ushort_t*)(PPB + (size_t)BB*SSEG*1024);
  ushort_t* Zb   = XINb + (size_t)NTOK*128;
  ushort_t* DTb  = Zb   + (size_t)NTOK*128;
  ushort_t* BTu  = DTb  + (size_t)NTOK*128;
  ushort_t* CTu  = BTu  + (size_t)NTOK*8;

  ushort_t* W1B   = CTu   + (size_t)NTOK*8;
  ushort_t* W2B   = W1B   + 256*128;
  ushort_t* PWB   = W2B   + 128*256;
  ushort_t* WIGB  = PWB   + 128*160;
  ushort_t* WDBCB = WIGB  + 3*256*128;
  ushort_t* WOUTB = WDBCB + 3*144*128;
  ushort_t* PW1B  = WOUTB + 3*128*128;
  ushort_t* PW2B  = PW1B  + 128*128;

  PJobs P;
  int nj = 0;
  auto add = [&](const float* src, ushort_t* dst, int N, int K, int Kpad, int rowofs, int Nw){
    P.j[nj].src = src; P.j[nj].dst = dst; P.j[nj].N = N; P.j[nj].K = K;
    P.j[nj].Kpad = Kpad; P.j[nj].rowofs = rowofs; P.j[nj].Nw = Nw; nj++;
  };
  add(enc_w1, W1B, 256, 115, 128, 0, 256);
  add(enc_w2, W2B, 128, 256, 256, 0, 128);
  add(proj_w, PWB, 128, 144, 160, 0, 128);
  for (int l = 0; l < NLD; l++)
    add(m_w_ig + (size_t)l*256*128, WIGB + (size_t)l*256*128, 256, 128, 128, 0, 256);
  for (int l = 0; l < NLD; l++){
    add(m_w_dt + (size_t)l*128*128, WDBCB + (size_t)l*144*128, 128, 128, 128, 0,   128);
    add(m_w_b  + (size_t)l*8*128,   WDBCB + (size_t)l*144*128,   8, 128, 128, 128,   8);
    add(m_w_c  + (size_t)l*8*128,   WDBCB + (size_t)l*144*128,   8, 128, 128, 136,   8);
  }
  for (int l = 0; l < NLD; l++)
    add(m_w_out + (size_t)l*128*128, WOUTB + (size_t)l*128*128, 128, 128, 128, 0, 128);
  add(pol_w1, PW1B, 128, 128, 128, 0, 128);
  add(pol_w2, PW2B,  19, 128, 128, 0,  32);

  k_prep<<<20*4, 256, 0, stream>>>(P);
  k_enc12p<<<NTOK/16, 256, 0, stream>>>(obs, W1B, enc_b1, enc_g1, enc_bb1,
      W2B, enc_b2, enc_g2, enc_bb2,
      emb, pact, PWB, proj_b, proj_g, proj_bb, X,
      m_ln_g, m_ln_b, WIGB, WDBCB, m_b_dt,
      XINb, Zb, DTb, BTu, CTu,
      m_a_log, HLA, PPA);

  const int carrygrid = BB*1024/64;    // 1024 blocks (2-level carry)
  const int scangrid  = NTOK/16;       // 2048 blocks x 256 thr

  // layer 0
  k_carry<<<carrygrid, 256, 0, stream>>>(HLA, PPA, h0);
  k_scan2p<<<scangrid, 256, 0, stream>>>(DTb, XINb, Zb, BTu, CTu,
      m_a_log, HLA, m_d, WOUTB, X,
      m_ln_g + 128, m_ln_b + 128,
      WIGB + (size_t)256*128, WDBCB + (size_t)144*128, m_b_dt + 128,
      m_a_log + 1024, HLB, PPB);
  // layer 1
  k_carry<<<carrygrid, 256, 0, stream>>>(HLB, PPB, h0 + (size_t)BB*1024);
  k_scan2p<<<scangrid, 256, 0, stream>>>(DTb, XINb, Zb, BTu, CTu,
      m_a_log + 1024, HLB, m_d + 128, WOUTB + (size_t)128*128, X,
      m_ln_g + 256, m_ln_b + 256,
      WIGB + (size_t)2*256*128, WDBCB + (size_t)2*144*128, m_b_dt + 256,
      m_a_log + 2048, HLA, PPA);
  // layer 2
  k_carry<<<carrygrid, 256, 0, stream>>>(HLA, PPA, h0 + (size_t)2*BB*1024);
  k_scan2h<<<scangrid, 256, 0, stream>>>(DTb, XINb, Zb, BTu, CTu,
      m_a_log + 2048, HLA, m_d + 256, WOUTB + (size_t)2*128*128, X,
      fn_g, fn_b, PW1B, pol_b1, pol_g, pol_bb, PW2B, pol_b2,
      (float*)d_out);
}

// Round 12
// 389.706 us; speedup vs baseline: 1.0880x; 1.0316x over previous
//
#include <hip/hip_runtime.h>
#include <math.h>

#define BB 64
#define TT 512
#define OBSD 115
#define DMD 128
#define DSD 8
#define NLD 3
#define EMBD 16
#define NAD 19
#define H1D 256
#define NTOK (BB*TT)
#define SSEG 32
#define TSEG (TT/SSEG)   // 16

typedef unsigned short ushort_t;
typedef __attribute__((ext_vector_type(8))) short short8;
typedef __attribute__((ext_vector_type(4))) float f32x4;

__device__ __forceinline__ float silu_f(float x){ return x / (1.f + __expf(-x)); }
__device__ __forceinline__ float softplus_f(float x){
  return fmaxf(x, 0.f) + log1pf(__expf(-fabsf(x)));
}
__device__ __forceinline__ ushort_t f2bf(float x){
  unsigned u = __float_as_uint(x);
  unsigned r = (u + 0x7fffu + ((u >> 16) & 1u)) >> 16;
  return (ushort_t)r;
}
__device__ __forceinline__ float b2f(ushort_t x){
  return __uint_as_float(((unsigned)x) << 16);
}
#define MFMA(a,b,c) __builtin_amdgcn_mfma_f32_16x16x32_bf16((a),(b),(c),0,0,0)
#define LOG2E 1.44269504f

// ---------------- k_prep ----------------
struct PJob { const float* src; ushort_t* dst; int N; int K; int Kpad; int rowofs; int Nw; };
struct PJobs { PJob j[20]; };

__global__ __launch_bounds__(256) void k_prep(PJobs P){
  const int job = blockIdx.x >> 2;
  const int sub = blockIdx.x & 3;
  PJob pj = P.j[job];
  const int elems = pj.Nw * pj.Kpad;
  for (int idx = sub*256 + threadIdx.x; idx < elems; idx += 4*256){
    int n = idx / pj.Kpad;
    int k = idx - n*pj.Kpad;
    float v = (n < pj.N && k < pj.K) ? pj.src[(size_t)n*pj.K + k] : 0.f;
    pj.dst[(size_t)(pj.rowofs + n)*pj.Kpad + k] = f2bf(v);
  }
}

// ======== k_enc12p: enc1+enc2+proj+LN(l0)+wig/wdbc(l0)+phaseA(l0), 16 tok/block ========
// (256,8)@VGPR32 = 97us beats (256,6)@VGPR40 = 102us (r5 vs r8 A/B); conflicts identical.
__global__ __launch_bounds__(256, 8) void k_enc12p(
    const float* __restrict__ obs, const ushort_t* __restrict__ w1b,
    const float* __restrict__ b1, const float* __restrict__ g1,
    const float* __restrict__ bb1,
    const ushort_t* __restrict__ w2b,
    const float* __restrict__ b2, const float* __restrict__ g2,
    const float* __restrict__ bb2,
    const float* __restrict__ emb, const int* __restrict__ pact,
    const ushort_t* __restrict__ pwb, const float* __restrict__ pb,
    const float* __restrict__ pg, const float* __restrict__ pbb,
    float* __restrict__ X,
    const float* __restrict__ lng, const float* __restrict__ lnb,
    const ushort_t* __restrict__ wigb, const ushort_t* __restrict__ wdbcb,
    const float* __restrict__ bdt,
    ushort_t* __restrict__ XINb, ushort_t* __restrict__ Zb,
    ushort_t* __restrict__ DTb, ushort_t* __restrict__ BTu, ushort_t* __restrict__ CTu,
    const float* __restrict__ alog0,
    float* __restrict__ HLOC, float* __restrict__ PPR)
{
  __shared__ __align__(16) char sm[15104];
  ushort_t* s_obs = (ushort_t*)sm;
  ushort_t* s_e1  = (ushort_t*)sm;
  ushort_t* s_xin = (ushort_t*)sm;
  ushort_t* s_dt  = (ushort_t*)(sm + 4352);
  ushort_t* s_a2  = (ushort_t*)(sm + 8448);
  ushort_t* s_btc = (ushort_t*)(sm + 13824);
  float2*   s_st  = (float2*)(sm + 14080);
  float2*   s_st2 = (float2*)(sm + 14592);

  const int tok0 = blockIdx.x * 16;
  const int bidx = blockIdx.x >> 5;
  const int ch   = blockIdx.x & 31;
  const int tid = threadIdx.x;
  const int lane = tid & 63, w = tid >> 6;
  const int q = lane >> 4, cn = lane & 15;

  // -- P1: stage obs (pad 115->128) + emb --
  {
    const int t = tid >> 4, kc = tid & 15;
    const float* op = obs + (size_t)(tok0 + t)*OBSD;
    short8 v;
    #pragma unroll
    for (int j = 0; j < 8; j++){
      int k = kc*8 + j;
      v[j] = (short)f2bf(k < OBSD ? op[k] : 0.f);
    }
    *(short8*)&s_obs[t*136 + kc*8] = v;
  }
  for (int e = tid; e < 16*32; e += 256){
    int t = e >> 5, k = e & 31;
    float v = 0.f;
    if (k < EMBD){ int a = pact[tok0 + t]; v = emb[(size_t)a*EMBD + k]; }
    s_a2[t*168 + 128 + k] = f2bf(v);
  }
  __syncthreads();

  // -- P2: GEMM1 (N=256, 4 tiles/wave) -> acc regs; in-reg LN stats --
  f32x4 acc[4];
  {
    short8 af[4];
    #pragma unroll
    for (int ks = 0; ks < 4; ks++)
      af[ks] = *(const short8*)&s_obs[cn*136 + ks*32 + q*8];
    #pragma unroll
    for (int nt = 0; nt < 4; nt++){
      const int n0 = (w*4 + nt) * 16;
      f32x4 a = {0.f,0.f,0.f,0.f};
      #pragma unroll
      for (int ks = 0; ks < 4; ks++){
        short8 bf = *(const short8*)&w1b[(size_t)(n0 + cn)*128 + ks*32 + q*8];
        a = MFMA(af[ks], bf, a);
      }
      float bv = b1[n0 + cn];
      #pragma unroll
      for (int r = 0; r < 4; r++) a[r] += bv;
      acc[nt] = a;
    }
    #pragma unroll
    for (int r = 0; r < 4; r++){
      float s = 0.f, s2 = 0.f;
      #pragma unroll
      for (int nt = 0; nt < 4; nt++){ float v = acc[nt][r]; s += v; s2 = fmaf(v, v, s2); }
      s += __shfl_xor(s, 1, 64); s2 += __shfl_xor(s2, 1, 64);
      s += __shfl_xor(s, 2, 64); s2 += __shfl_xor(s2, 2, 64);
      s += __shfl_xor(s, 4, 64); s2 += __shfl_xor(s2, 4, 64);
      s += __shfl_xor(s, 8, 64); s2 += __shfl_xor(s2, 8, 64);
      if (cn == 0) s_st[(q*4 + r)*4 + w] = make_float2(s, s2);
    }
  }
  __syncthreads();   // s_obs dead

  // -- P3: normalize(256) + silu -> s_e1 --
  {
    float mu[4], rs[4];
    #pragma unroll
    for (int r = 0; r < 4; r++){
      const int row = q*4 + r;
      float2 p0 = s_st[row*4+0], p1 = s_st[row*4+1];
      float2 p2 = s_st[row*4+2], p3 = s_st[row*4+3];
      float s = p0.x+p1.x+p2.x+p3.x, s2 = p0.y+p1.y+p2.y+p3.y;
      float m = s * (1.f/256.f);
      mu[r] = m;
      rs[r] = rsqrtf(s2 * (1.f/256.f) - m*m + 1e-5f);
    }
    #pragma unroll
    for (int nt = 0; nt < 4; nt++){
      const int col = (w*4 + nt)*16 + cn;
      float gg = g1[col], bbv = bb1[col];
      #pragma unroll
      for (int r = 0; r < 4; r++){
        float v = (acc[nt][r] - mu[r]) * rs[r] * gg + bbv;
        s_e1[(q*4 + r)*264 + col] = f2bf(silu_f(v));
      }
    }
  }
  __syncthreads();

  // -- P4: GEMM2 (K=256, N=128, 2 tiles/wave) -> acc2; stats --
  f32x4 acc2[2];
  {
    short8 af2[8];
    #pragma unroll
    for (int ks = 0; ks < 8; ks++)
      af2[ks] = *(const short8*)&s_e1[cn*264 + ks*32 + q*8];
    #pragma unroll
    for (int nt = 0; nt < 2; nt++){
      const int n0 = (w*2 + nt) * 16;
      f32x4 a = {0.f,0.f,0.f,0.f};
      #pragma unroll
      for (int ks = 0; ks < 8; ks++){
        short8 bf = *(const short8*)&w2b[(size_t)(n0 + cn)*256 + ks*32 + q*8];
        a = MFMA(af2[ks], bf, a);
      }
      float bv = b2[n0 + cn];
      #pragma unroll
      for (int r = 0; r < 4; r++) a[r] += bv;
      acc2[nt] = a;
    }
    #pragma unroll
    for (int r = 0; r < 4; r++){
      float s = 0.f, s2 = 0.f;
      #pragma unroll
      for (int nt = 0; nt < 2; nt++){ float v = acc2[nt][r]; s += v; s2 = fmaf(v, v, s2); }
      s += __shfl_xor(s, 1, 64); s2 += __shfl_xor(s2, 1, 64);
      s += __shfl_xor(s, 2, 64); s2 += __shfl_xor(s2, 2, 64);
      s += __shfl_xor(s, 4, 64); s2 += __shfl_xor(s2, 4, 64);
      s += __shfl_xor(s, 8, 64); s2 += __shfl_xor(s2, 8, 64);
      if (cn == 0) s_st[(q*4 + r)*4 + w] = make_float2(s, s2);
    }
  }
  __syncthreads();

  // -- P5: normalize(g2/bb2) -> s_a2 cols [0,128) --
  {
    float mu[4], rs[4];
    #pragma unroll
    for (int r = 0; r < 4; r++){
      const int row = q*4 + r;
      float2 p0 = s_st[row*4+0], p1 = s_st[row*4+1];
      float2 p2 = s_st[row*4+2], p3 = s_st[row*4+3];
      float s = p0.x+p1.x+p2.x+p3.x, s2 = p0.y+p1.y+p2.y+p3.y;
      float m = s * (1.f/128.f);
      mu[r] = m;
      rs[r] = rsqrtf(s2 * (1.f/128.f) - m*m + 1e-5f);
    }
    #pragma unroll
    for (int nt = 0; nt < 2; nt++){
      const int col = (w*2 + nt)*16 + cn;
      float gg = g2[col], bbv = bb2[col];
      #pragma unroll
      for (int r = 0; r < 4; r++){
        float v = (acc2[nt][r] - mu[r]) * rs[r] * gg + bbv;
        s_a2[(q*4 + r)*168 + col] = f2bf(v);
      }
    }
  }
  __syncthreads();

  // -- P6: proj GEMM (K=160) -> acc3; stats --
  f32x4 acc3[2];
  {
    short8 af3[5];
    #pragma unroll
    for (int ks = 0; ks < 5; ks++)
      af3[ks] = *(const short8*)&s_a2[cn*168 + ks*32 + q*8];
    #pragma unroll
    for (int nt = 0; nt < 2; nt++){
      const int n0 = (w*2 + nt) * 16;
      f32x4 a = {0.f,0.f,0.f,0.f};
      #pragma unroll
      for (int ks = 0; ks < 5; ks++){
        short8 bf = *(const short8*)&pwb[(size_t)(n0 + cn)*160 + ks*32 + q*8];
        a = MFMA(af3[ks], bf, a);
      }
      float bv = pb[n0 + cn];
      #pragma unroll
      for (int r = 0; r < 4; r++) a[r] += bv;
      acc3[nt] = a;
    }
    #pragma unroll
    for (int r = 0; r < 4; r++){
      float s = 0.f, s2 = 0.f;
      #pragma unroll
      for (int nt = 0; nt < 2; nt++){ float v = acc3[nt][r]; s += v; s2 = fmaf(v, v, s2); }
      s += __shfl_xor(s, 1, 64); s2 += __shfl_xor(s2, 1, 64);
      s += __shfl_xor(s, 2, 64); s2 += __shfl_xor(s2, 2, 64);
      s += __shfl_xor(s, 4, 64); s2 += __shfl_xor(s2, 4, 64);
      s += __shfl_xor(s, 8, 64); s2 += __shfl_xor(s2, 8, 64);
      if (cn == 0) s_st[(q*4 + r)*4 + w] = make_float2(s, s2);
    }
  }
  __syncthreads();

  // -- P7: normalize(pg/pbb)+silu -> acc3 + X; stats2 --
  {
    float mu[4], rs[4];
    #pragma unroll
    for (int r = 0; r < 4; r++){
      const int row = q*4 + r;
      float2 p0 = s_st[row*4+0], p1 = s_st[row*4+1];
      float2 p2 = s_st[row*4+2], p3 = s_st[row*4+3];
      float s = p0.x+p1.x+p2.x+p3.x, s2 = p0.y+p1.y+p2.y+p3.y;
      float m = s * (1.f/128.f);
      mu[r] = m;
      rs[r] = rsqrtf(s2 * (1.f/128.f) - m*m + 1e-5f);
    }
    float ps[4] = {0.f,0.f,0.f,0.f}, ps2[4] = {0.f,0.f,0.f,0.f};
    #pragma unroll
    for (int nt = 0; nt < 2; nt++){
      const int col = (w*2 + nt)*16 + cn;
      float gg = pg[col], bbv = pbb[col];
      #pragma unroll
      for (int r = 0; r < 4; r++){
        float v = (acc3[nt][r] - mu[r]) * rs[r] * gg + bbv;
        v = silu_f(v);
        acc3[nt][r] = v;
        X[(size_t)(tok0 + q*4 + r)*128 + col] = v;
        ps[r] += v; ps2[r] = fmaf(v, v, ps2[r]);
      }
    }
    #pragma unroll
    for (int r = 0; r < 4; r++){
      float s = ps[r], s2 = ps2[r];
      s += __shfl_xor(s, 1, 64); s2 += __shfl_xor(s2, 1, 64);
      s += __shfl_xor(s, 2, 64); s2 += __shfl_xor(s2, 2, 64);
      s += __shfl_xor(s, 4, 64); s2 += __shfl_xor(s2, 4, 64);
      s += __shfl_xor(s, 8, 64); s2 += __shfl_xor(s2, 8, 64);
      if (cn == 0) s_st2[(q*4 + r)*4 + w] = make_float2(s, s2);
    }
  }
  __syncthreads();

  // -- P8: mamba LN (lng/lnb) -> s_a2 cols [0,128) --
  {
    float mu[4], rs[4];
    #pragma unroll
    for (int r = 0; r < 4; r++){
      const int row = q*4 + r;
      float2 p0 = s_st2[row*4+0], p1 = s_st2[row*4+1];
      float2 p2 = s_st2[row*4+2], p3 = s_st2[row*4+3];
      float s = p0.x+p1.x+p2.x+p3.x, s2 = p0.y+p1.y+p2.y+p3.y;
      float m = s * (1.f/128.f);
      mu[r] = m;
      rs[r] = rsqrtf(s2 * (1.f/128.f) - m*m + 1e-5f);
    }
    #pragma unroll
    for (int nt = 0; nt < 2; nt++){
      const int col = (w*2 + nt)*16 + cn;
      float gg = lng[col], bbv = lnb[col];
      #pragma unroll
      for (int r = 0; r < 4; r++){
        float v = (acc3[nt][r] - mu[r]) * rs[r] * gg + bbv;
        s_a2[(q*4 + r)*168 + col] = f2bf(v);
      }
    }
  }
  __syncthreads();

  // -- P9: wig GEMM (N=256, 4 tiles/wave) --
  {
    short8 af[4];
    #pragma unroll
    for (int ks = 0; ks < 4; ks++)
      af[ks] = *(const short8*)&s_a2[cn*168 + ks*32 + q*8];
    #pragma unroll
    for (int i = 0; i < 4; i++){
      const int n0 = (w*4 + i) * 16;
      f32x4 a = {0.f,0.f,0.f,0.f};
      #pragma unroll
      for (int ks = 0; ks < 4; ks++){
        short8 bf = *(const short8*)&wigb[(size_t)(n0 + cn)*128 + ks*32 + q*8];
        a = MFMA(af[ks], bf, a);
      }
      if (n0 < 128){
        #pragma unroll
        for (int r = 0; r < 4; r++){
          int tr = q*4 + r;
          ushort_t bb = f2bf(a[r]);
          XINb[(size_t)(tok0 + tr)*128 + n0 + cn] = bb;
          s_xin[tr*136 + n0 + cn] = bb;
        }
      } else {
        #pragma unroll
        for (int r = 0; r < 4; r++){
          int tr = q*4 + r;
          Zb[(size_t)(tok0 + tr)*128 + (n0 - 128) + cn] = f2bf(a[r]);
        }
      }
    }
  }
  __syncthreads();

  // -- P10: wdbc GEMM (N=144, nt=w..9 step 4) --
  {
    short8 af2[4];
    #pragma unroll
    for (int ks = 0; ks < 4; ks++)
      af2[ks] = *(const short8*)&s_xin[cn*136 + ks*32 + q*8];
    for (int nt = w; nt < 9; nt += 4){
      const int n0 = nt * 16;
      f32x4 a = {0.f,0.f,0.f,0.f};
      #pragma unroll
      for (int ks = 0; ks < 4; ks++){
        short8 bf = *(const short8*)&wdbcb[(size_t)(n0 + cn)*128 + ks*32 + q*8];
        a = MFMA(af2[ks], bf, a);
      }
      const int col = n0 + cn;
      if (col < 128){
        float bd = bdt[col];
        #pragma unroll
        for (int r = 0; r < 4; r++){
          int tr = q*4 + r;
          ushort_t dv = f2bf(softplus_f(a[r] + bd));
          DTb[(size_t)(tok0 + tr)*128 + col] = dv;
          s_dt[tr*136 + col] = dv;
        }
      } else if (col < 136){
        #pragma unroll
        for (int r = 0; r < 4; r++){
          int tr = q*4 + r;
          ushort_t bb = f2bf(a[r]);
          BTu[(size_t)(tok0 + tr)*8 + (col - 128)] = bb;
          s_btc[tr*8 + (col - 128)] = bb;
        }
      } else {
        #pragma unroll
        for (int r = 0; r < 4; r++)
          CTu[(size_t)(tok0 + q*4 + r)*8 + (col - 136)] = f2bf(a[r]);
      }
    }
  }
  __syncthreads();

  // -- P11: phase A (layer 0): thread=(d, s-half), 4 states, 16 tokens --
  {
    const int d = tid & 127, sh = tid >> 7;
    float A2c[4], hh[4], pp[4];
    #pragma unroll
    for (int j = 0; j < 4; j++){
      A2c[j] = -__expf(alog0[d*8 + sh*4 + j]) * LOG2E;
      hh[j] = 0.f; pp[j] = 1.f;
    }
    #pragma unroll 4
    for (int t = 0; t < 16; t++){
      float dt = b2f(s_dt[t*136 + d]);
      float wv = dt * b2f(s_xin[t*136 + d]);
      #pragma unroll
      for (int j = 0; j < 4; j++){
        float dA = exp2f(dt * A2c[j]);
        hh[j] = fmaf(dA, hh[j], wv * b2f(s_btc[t*8 + sh*4 + j]));
        pp[j] *= dA;
      }
    }
    const size_t o = ((size_t)bidx*SSEG + ch)*1024 + d*8 + sh*4;
    #pragma unroll
    for (int j = 0; j < 4; j++){ HLOC[o+j] = hh[j]; PPR[o+j] = pp[j]; }
  }
}

// ---- k_carry: two-level exclusive prefix; 64 elems/block, 4 sub-ranges of 8 chunks ----
__global__ __launch_bounds__(256) void k_carry(
    float* __restrict__ HL, const float* __restrict__ PP,
    const float* __restrict__ h0g)
{
  __shared__ float s_P[3*64], s_H[3*64];
  const int e   = threadIdx.x & 63;
  const int sub = threadIdx.x >> 6;
  const int idx = blockIdx.x*64 + e;
  const size_t base = (size_t)(idx >> 10) * (SSEG*1024) + (idx & 1023);
  const int c0 = sub*8;

  float hl[8], pp[8];
  #pragma unroll
  for (int c = 0; c < 8; c++){
    hl[c] = HL[base + (size_t)(c0+c)*1024];
    pp[c] = PP[base + (size_t)(c0+c)*1024];
  }
  float Pc = 1.f, Hc = 0.f;
  #pragma unroll
  for (int c = 0; c < 8; c++){
    Hc = fmaf(pp[c], Hc, hl[c]);
    Pc *= pp[c];
  }
  if (sub < 3){ s_P[sub*64 + e] = Pc; s_H[sub*64 + e] = Hc; }
  float h = h0g[idx];
  __syncthreads();
  #pragma unroll
  for (int s = 0; s < 3; s++){
    if (s < sub) h = fmaf(s_P[s*64 + e], h, s_H[s*64 + e]);
  }
  #pragma unroll
  for (int c = 0; c < 8; c++){
    HL[base + (size_t)(c0+c)*1024] = h;
    h = fmaf(pp[c], h, hl[c]);
  }
}

// ======== phase B over 16 tokens: all-wave scan + wout + residual + in-reg LN stats ====
// (256,8): scans were capped at 6 blocks/CU against an 8-block/CU grid -> 1.33x tail
// elongation. r5-vs-r8 A/B on enc12p showed the VGPR-32 squeeze is a net win.
// LDS (bytes):
//  [0,4096) s_dtS ; [4096,8192) s_xiS ; [8192,12288) s_zS   [dead after scan]
//  [0,8320)      s_x f32 16x130 (wout out; aliases staging)
//  [0,4352)      s_xin bf16 (wig out, late) ; [4352,8704) s_dt2 (wdbc out, late)
//  [12288,16640) s_a bf16 16x136
//  [16640,16896) s_bt ; [16896,17152) s_ct
//  [17152,17664) s_st float2[16][4]
#define SMB 17664

__device__ __forceinline__ void phaseB16(
    const ushort_t* DTb, const ushort_t* XINb, const ushort_t* Zb,
    const ushort_t* BTu, const ushort_t* CTu,
    const float* __restrict__ alog, const float* __restrict__ HLpre,
    const float* __restrict__ dpar, const ushort_t* __restrict__ woutb,
    float* __restrict__ X, char* sm, int b, int seg, int tid)
{
  ushort_t* s_dtS = (ushort_t*)sm;
  ushort_t* s_xiS = (ushort_t*)(sm + 4096);
  ushort_t* s_zS  = (ushort_t*)(sm + 8192);
  float*    s_x   = (float*)sm;
  ushort_t* s_a   = (ushort_t*)(sm + 12288);
  ushort_t* s_bt  = (ushort_t*)(sm + 16640);
  ushort_t* s_ct  = (ushort_t*)(sm + 16896);
  float2*   s_st  = (float2*)(sm + 17152);

  const int lane = tid & 63, w = tid >> 6, q = lane >> 4, cn = lane & 15;
  const size_t segtok = (size_t)b*TT + seg*TSEG;

  // stage dt/xin/z (16x128 bf16 each = 256 uint4) + bt/ct
  ((uint4*)s_dtS)[tid] = ((const uint4*)(DTb  + segtok*128))[tid];
  ((uint4*)s_xiS)[tid] = ((const uint4*)(XINb + segtok*128))[tid];
  ((uint4*)s_zS )[tid] = ((const uint4*)(Zb   + segtok*128))[tid];
  if (tid < 64){
    ((unsigned*)s_bt)[tid] = ((const unsigned*)(BTu + segtok*8))[tid];
    ((unsigned*)s_ct)[tid] = ((const unsigned*)(CTu + segtok*8))[tid];
  }

  // recurrence state: all 256 threads; (d2, sh) = (w*32 + lane&31, lane>>5)
  const int d2 = (w << 5) | (lane & 31);
  const int sh = lane >> 5;
  float A2h[4], h[4];
  {
    const size_t o = ((size_t)b*SSEG + seg)*1024 + d2*8 + sh*4;
    float4 hv = *(const float4*)(HLpre + o);
    h[0]=hv.x; h[1]=hv.y; h[2]=hv.z; h[3]=hv.w;
    #pragma unroll
    for (int j = 0; j < 4; j++)
      A2h[j] = -__expf(alog[d2*8 + sh*4 + j]) * LOG2E;
  }
  const float dp = dpar[d2];
  __syncthreads();

  // scan: 4 states/thread; cross-half y combine via shfl_xor 32
  #pragma unroll 4
  for (int t = 0; t < 16; t++){
    float dt = b2f(s_dtS[t*128 + d2]);
    float xi = b2f(s_xiS[t*128 + d2]);
    float zv = b2f(s_zS [t*128 + d2]);
    float wv = dt * xi;
    float yp = 0.f;
    #pragma unroll
    for (int j = 0; j < 4; j++){
      float dA = exp2f(dt * A2h[j]);
      h[j] = fmaf(dA, h[j], wv * b2f(s_bt[t*8 + sh*4 + j]));
      yp = fmaf(h[j], b2f(s_ct[t*8 + sh*4 + j]), yp);
    }
    float y = yp + __shfl_xor(yp, 32, 64);
    float ssm = y * silu_f(zv) + xi * dp;
    if (sh == 0) s_a[t*136 + d2] = f2bf(ssm);
  }
  __syncthreads();   // staging dead; s_x writable

  // wout GEMM (N=128, 2 tiles/wave) + residual -> s_x + X; in-reg LN stats
  {
    short8 af[4];
    #pragma unroll
    for (int ks = 0; ks < 4; ks++)
      af[ks] = *(const short8*)&s_a[cn*136 + ks*32 + q*8];
    float ps[4] = {0.f,0.f,0.f,0.f}, ps2[4] = {0.f,0.f,0.f,0.f};
    #pragma unroll
    for (int i = 0; i < 2; i++){
      const int n0 = (w*2 + i) * 16;
      short8 bf[4];
      #pragma unroll
      for (int ks = 0; ks < 4; ks++)
        bf[ks] = *(const short8*)&woutb[(size_t)(n0+cn)*128 + ks*32 + q*8];
      f32x4 acc = {0.f,0.f,0.f,0.f};
      #pragma unroll
      for (int ks = 0; ks < 4; ks++) acc = MFMA(af[ks], bf[ks], acc);
      #pragma unroll
      for (int r = 0; r < 4; r++){
        const int tr = q*4 + r;
        const size_t g = (segtok + tr)*128 + n0 + cn;
        float xn = X[g] + acc[r];
        X[g] = xn;
        s_x[tr*130 + n0 + cn] = xn;
        ps[r] += xn; ps2[r] = fmaf(xn, xn, ps2[r]);
      }
    }
    #pragma unroll
    for (int r = 0; r < 4; r++){
      float s = ps[r], s2 = ps2[r];
      s += __shfl_xor(s, 1, 64); s2 += __shfl_xor(s2, 1, 64);
      s += __shfl_xor(s, 2, 64); s2 += __shfl_xor(s2, 2, 64);
      s += __shfl_xor(s, 4, 64); s2 += __shfl_xor(s2, 4, 64);
      s += __shfl_xor(s, 8, 64); s2 += __shfl_xor(s2, 8, 64);
      if (cn == 0) s_st[(q*4 + r)*4 + w] = make_float2(s, s2);
    }
  }
  __syncthreads();
}

// ---- k_scan2p: 16-token block; phaseB, LN, wig, wdbc, phaseA(next) ----
__global__ __launch_bounds__(256, 8) void k_scan2p(
    ushort_t* DTb, ushort_t* XINb, ushort_t* Zb,
    ushort_t* BTu, ushort_t* CTu,
    const float* __restrict__ alog, const float* __restrict__ HLpre,
    const float* __restrict__ dpar, const ushort_t* __restrict__ woutb,
    float* __restrict__ X,
    const float* __restrict__ lng, const float* __restrict__ lnb,
    const ushort_t* __restrict__ wigb, const ushort_t* __restrict__ wdbcb,
    const float* __restrict__ bdt,
    const float* __restrict__ alogn,
    float* __restrict__ HLo, float* __restrict__ PPo)
{
  __shared__ __align__(16) char sm[SMB];
  const int tid = threadIdx.x;
  float*    s_x   = (float*)sm;
  ushort_t* s_xin = (ushort_t*)sm;
  ushort_t* s_dt2 = (ushort_t*)(sm + 4352);
  ushort_t* s_a   = (ushort_t*)(sm + 12288);
  ushort_t* s_btc = (ushort_t*)(sm + 16640);
  float2*   s_st  = (float2*)(sm + 17152);

  const int b = blockIdx.x >> 5;
  const int seg = blockIdx.x & 31;
  const int lane = tid & 63, w = tid >> 6, q = lane >> 4, cn = lane & 15;
  const size_t segtok = (size_t)b*TT + seg*TSEG;

  phaseB16(DTb, XINb, Zb, BTu, CTu, alog, HLpre, dpar, woutb, X, sm, b, seg, tid);

  // P4: normalize (lng/lnb) -> s_a
  {
    const int d = tid & 127, half = tid >> 7;
    float g = lng[d], c0v = lnb[d];
    #pragma unroll
    for (int tt = 0; tt < 8; tt++){
      const int t = half*8 + tt;
      float2 p0 = s_st[t*4+0], p1 = s_st[t*4+1];
      float2 p2 = s_st[t*4+2], p3 = s_st[t*4+3];
      float ssum = p0.x+p1.x+p2.x+p3.x, ss2 = p0.y+p1.y+p2.y+p3.y;
      float mu = ssum * (1.f/128.f);
      float rs = rsqrtf(ss2 * (1.f/128.f) - mu*mu + 1e-5f);
      float v = (s_x[t*130 + d] - mu) * rs * g + c0v;
      s_a[t*136 + d] = f2bf(v);
    }
  }
  __syncthreads();

  // P5: wig GEMM (N=256, 4 tiles/wave); writes s_xin (aliases dead s_x) + XINb/Zb
  {
    short8 af[4];
    #pragma unroll
    for (int ks = 0; ks < 4; ks++)
      af[ks] = *(const short8*)&s_a[cn*136 + ks*32 + q*8];
    #pragma unroll
    for (int i = 0; i < 4; i++){
      const int n0 = (w*4 + i) * 16;
      short8 bf[4];
      #pragma unroll
      for (int ks = 0; ks < 4; ks++)
        bf[ks] = *(const short8*)&wigb[(size_t)(n0+cn)*128 + ks*32 + q*8];
      f32x4 acc = {0.f,0.f,0.f,0.f};
      #pragma unroll
      for (int ks = 0; ks < 4; ks++) acc = MFMA(af[ks], bf[ks], acc);
      if (n0 < 128){
        #pragma unroll
        for (int r = 0; r < 4; r++){
          const int tr = q*4 + r;
          ushort_t bb = f2bf(acc[r]);
          XINb[(segtok + tr)*128 + n0 + cn] = bb;
          s_xin[tr*136 + n0 + cn] = bb;
        }
      } else {
        #pragma unroll
        for (int r = 0; r < 4; r++){
          const int tr = q*4 + r;
          Zb[(segtok + tr)*128 + (n0-128) + cn] = f2bf(acc[r]);
        }
      }
    }
  }
  __syncthreads();

  // P6: wdbc GEMM; fills s_dt2 / s_btc
  {
    short8 af2[4];
    #pragma unroll
    for (int ks = 0; ks < 4; ks++)
      af2[ks] = *(const short8*)&s_xin[cn*136 + ks*32 + q*8];
    for (int nt = w; nt < 9; nt += 4){
      const int n0 = nt * 16;
      short8 bf[4];
      #pragma unroll
      for (int ks = 0; ks < 4; ks++)
        bf[ks] = *(const short8*)&wdbcb[(size_t)(n0+cn)*128 + ks*32 + q*8];
      f32x4 acc = {0.f,0.f,0.f,0.f};
      #pragma unroll
      for (int ks = 0; ks < 4; ks++) acc = MFMA(af2[ks], bf[ks], acc);
      const int col = n0 + cn;
      if (col < 128){
        float bd = bdt[col];
        #pragma unroll
        for (int r = 0; r < 4; r++){
          const int tr = q*4 + r;
          ushort_t dv = f2bf(softplus_f(acc[r] + bd));
          DTb[(segtok + tr)*128 + col] = dv;
          s_dt2[tr*136 + col] = dv;
        }
      } else if (col < 136){
        #pragma unroll
        for (int r = 0; r < 4; r++){
          const int tr = q*4 + r;
          ushort_t bb = f2bf(acc[r]);
          BTu[(segtok + tr)*8 + (col-128)] = bb;
          s_btc[tr*8 + (col-128)] = bb;
        }
      } else {
        #pragma unroll
        for (int r = 0; r < 4; r++)
          CTu[(segtok + q*4 + r)*8 + (col-136)] = f2bf(acc[r]);
      }
    }
  }
  __syncthreads();

  // P7: phase A (next layer): thread=(d, s-half), 4 states, 16 tokens
  {
    const int d = tid & 127, sh = tid >> 7;
    float A2n[4], hh[4], pp[4];
    #pragma unroll
    for (int j = 0; j < 4; j++){
      A2n[j] = -__expf(alogn[d*8 + sh*4 + j]) * LOG2E;
      hh[j] = 0.f; pp[j] = 1.f;
    }
    #pragma unroll 4
    for (int t = 0; t < 16; t++){
      float dt = b2f(s_dt2[t*136 + d]);
      float wv = dt * b2f(s_xin[t*136 + d]);
      #pragma unroll
      for (int j = 0; j < 4; j++){
        float dA = exp2f(dt * A2n[j]);
        hh[j] = fmaf(dA, hh[j], wv * b2f(s_btc[t*8 + sh*4 + j]));
        pp[j] *= dA;
      }
    }
    const size_t o = ((size_t)b*SSEG + seg)*1024 + d*8 + sh*4;
    #pragma unroll
    for (int j = 0; j < 4; j++){ HLo[o+j] = hh[j]; PPo[o+j] = pp[j]; }
  }
}

// ---- k_scan2h: 16-token block; phaseB, LNfn, pw1(+stats), LN+silu, pw2 ----
__global__ __launch_bounds__(256, 8) void k_scan2h(
    const ushort_t* DTb, const ushort_t* XINb, const ushort_t* Zb,
    const ushort_t* BTu, const ushort_t* CTu,
    const float* __restrict__ alog, const float* __restrict__ HLpre,
    const float* __restrict__ dpar, const ushort_t* __restrict__ woutb,
    float* __restrict__ X,
    const float* __restrict__ fng, const float* __restrict__ fnb,
    const ushort_t* __restrict__ pw1b, const float* __restrict__ pb1,
    const float* __restrict__ pg, const float* __restrict__ pbb,
    const ushort_t* __restrict__ pw2b, const float* __restrict__ pb2,
    float* __restrict__ out)
{
  __shared__ __align__(16) char sm[SMB];
  const int tid = threadIdx.x;
  float*    s_x  = (float*)sm;
  ushort_t* s_a  = (ushort_t*)(sm + 12288);
  float2*   s_st = (float2*)(sm + 17152);

  const int b = blockIdx.x >> 5;
  const int seg = blockIdx.x & 31;
  const int lane = tid & 63, w = tid >> 6, q = lane >> 4, cn = lane & 15;
  const size_t segtok = (size_t)b*TT + seg*TSEG;

  phaseB16((ushort_t*)DTb, (ushort_t*)XINb, (ushort_t*)Zb,
           (ushort_t*)BTu, (ushort_t*)CTu, alog, HLpre,
           dpar, woutb, X, sm, b, seg, tid);

  // P4: LN_fn -> s_a
  {
    const int d = tid & 127, half = tid >> 7;
    float g = fng[d], c0v = fnb[d];
    #pragma unroll
    for (int tt = 0; tt < 8; tt++){
      const int t = half*8 + tt;
      float2 p0 = s_st[t*4+0], p1 = s_st[t*4+1];
      float2 p2 = s_st[t*4+2], p3 = s_st[t*4+3];
      float ssum = p0.x+p1.x+p2.x+p3.x, ss2 = p0.y+p1.y+p2.y+p3.y;
      float mu = ssum * (1.f/128.f);
      float rs = rsqrtf(ss2 * (1.f/128.f) - mu*mu + 1e-5f);
      float v = (s_x[t*130 + d] - mu) * rs * g + c0v;
      s_a[t*136 + d] = f2bf(v);
    }
  }
  __syncthreads();

  // P5: pw1 GEMM (N=128, 2 tiles/wave) -> s_x (+bias); in-reg stats
  {
    short8 af[4];
    #pragma unroll
    for (int ks = 0; ks < 4; ks++)
      af[ks] = *(const short8*)&s_a[cn*136 + ks*32 + q*8];
    float ps[4] = {0.f,0.f,0.f,0.f}, ps2[4] = {0.f,0.f,0.f,0.f};
    #pragma unroll
    for (int i = 0; i < 2; i++){
      const int n0 = (w*2 + i) * 16;
      short8 bf[4];
      #pragma unroll
      for (int ks = 0; ks < 4; ks++)
        bf[ks] = *(const short8*)&pw1b[(size_t)(n0+cn)*128 + ks*32 + q*8];
      float bias = pb1[n0 + cn];
      f32x4 acc = {0.f,0.f,0.f,0.f};
      #pragma unroll
      for (int ks = 0; ks < 4; ks++) acc = MFMA(af[ks], bf[ks], acc);
      #pragma unroll
      for (int r = 0; r < 4; r++){
        float xv = acc[r] + bias;
        s_x[(q*4 + r)*130 + n0 + cn] = xv;
        ps[r] += xv; ps2[r] = fmaf(xv, xv, ps2[r]);
      }
    }
    #pragma unroll
    for (int r = 0; r < 4; r++){
      float s = ps[r], s2 = ps2[r];
      s += __shfl_xor(s, 1, 64); s2 += __shfl_xor(s2, 1, 64);
      s += __shfl_xor(s, 2, 64); s2 += __shfl_xor(s2, 2, 64);
      s += __shfl_xor(s, 4, 64); s2 += __shfl_xor(s2, 4, 64);
      s += __shfl_xor(s, 8, 64); s2 += __shfl_xor(s2, 8, 64);
      if (cn == 0) s_st[(q*4 + r)*4 + w] = make_float2(s, s2);
    }
  }
  __syncthreads();

  // P6: LN(pg/pbb)+silu -> s_a
  {
    const int d = tid & 127, half = tid >> 7;
    float g = pg[d], c0v = pbb[d];
    #pragma unroll
    for (int tt = 0; tt < 8; tt++){
      const int t = half*8 + tt;
      float2 p0 = s_st[t*4+0], p1 = s_st[t*4+1];
      float2 p2 = s_st[t*4+2], p3 = s_st[t*4+3];
      float ssum = p0.x+p1.x+p2.x+p3.x, ss2 = p0.y+p1.y+p2.y+p3.y;
      float mu = ssum * (1.f/128.f);
      float rs = rsqrtf(ss2 * (1.f/128.f) - mu*mu + 1e-5f);
      float v = (s_x[t*130 + d] - mu) * rs * g + c0v;
      s_a[t*136 + d] = f2bf(silu_f(v));
    }
  }
  __syncthreads();

  // P7: pw2 GEMM (N=32; waves 0,1; cols<19 stored)
  if (w < 2){
    short8 af[4];
    #pragma unroll
    for (int ks = 0; ks < 4; ks++)
      af[ks] = *(const short8*)&s_a[cn*136 + ks*32 + q*8];
    const int n0 = w * 16;
    short8 bf[4];
    #pragma unroll
    for (int ks = 0; ks < 4; ks++)
      bf[ks] = *(const short8*)&pw2b[(size_t)(n0+cn)*128 + ks*32 + q*8];
    const int col = n0 + cn;
    f32x4 acc = {0.f,0.f,0.f,0.f};
    #pragma unroll
    for (int ks = 0; ks < 4; ks++) acc = MFMA(af[ks], bf[ks], acc);
    if (col < NAD){
      float bias = pb2[col];
      #pragma unroll
      for (int r = 0; r < 4; r++)
        out[(segtok + q*4 + r)*NAD + col] = acc[r] + bias;
    }
  }
}

extern "C" void kernel_launch(void* const* d_in, const int* in_sizes, int n_in,
                              void* d_out, int out_size, void* d_ws, size_t ws_size,
                              hipStream_t stream) {
  const float* obs    = (const float*)d_in[0];
  const float* h0     = (const float*)d_in[1];
  const float* enc_w1 = (const float*)d_in[2];
  const float* enc_b1 = (const float*)d_in[3];
  const float* enc_g1 = (const float*)d_in[4];
  const float* enc_bb1= (const float*)d_in[5];
  const float* enc_w2 = (const float*)d_in[6];
  const float* enc_b2 = (const float*)d_in[7];
  const float* enc_g2 = (const float*)d_in[8];
  const float* enc_bb2= (const float*)d_in[9];
  const float* emb    = (const float*)d_in[10];
  const float* proj_w = (const float*)d_in[11];
  const float* proj_b = (const float*)d_in[12];
  const float* proj_g = (const float*)d_in[13];
  const float* proj_bb= (const float*)d_in[14];
  const float* m_ln_g = (const float*)d_in[15];
  const float* m_ln_b = (const float*)d_in[16];
  const float* m_w_ig = (const float*)d_in[17];
  const float* m_w_dt = (const float*)d_in[18];
  const float* m_b_dt = (const float*)d_in[19];
  const float* m_a_log= (const float*)d_in[20];
  const float* m_w_b  = (const float*)d_in[21];
  const float* m_w_c  = (const float*)d_in[22];
  const float* m_d    = (const float*)d_in[23];
  const float* m_w_out= (const float*)d_in[24];
  const float* fn_g   = (const float*)d_in[25];
  const float* fn_b   = (const float*)d_in[26];
  const float* pol_w1 = (const float*)d_in[27];
  const float* pol_b1 = (const float*)d_in[28];
  const float* pol_g  = (const float*)d_in[29];
  const float* pol_bb = (const float*)d_in[30];
  const float* pol_w2 = (const float*)d_in[31];
  const float* pol_b2 = (const float*)d_in[32];
  const int*   pact   = (const int*)d_in[33];

  float* ws  = (float*)d_ws;
  float* X    = ws;
  float* HLA  = X + (size_t)NTOK*128;
  float* PPA  = HLA + (size_t)BB*SSEG*1024;
  float* HLB  = PPA + (size_t)BB*SSEG*1024;
  float* PPB  = HLB + (size_t)BB*SSEG*1024;
  ushort_t* XINb = (ushort_t*)(PPB + (size_t)BB*SSEG*1024);
  ushort_t* Zb   = XINb + (size_t)NTOK*128;
  ushort_t* DTb  = Zb   + (size_t)NTOK*128;
  ushort_t* BTu  = DTb  + (size_t)NTOK*128;
  ushort_t* CTu  = BTu  + (size_t)NTOK*8;

  ushort_t* W1B   = CTu   + (size_t)NTOK*8;
  ushort_t* W2B   = W1B   + 256*128;
  ushort_t* PWB   = W2B   + 128*256;
  ushort_t* WIGB  = PWB   + 128*160;
  ushort_t* WDBCB = WIGB  + 3*256*128;
  ushort_t* WOUTB = WDBCB + 3*144*128;
  ushort_t* PW1B  = WOUTB + 3*128*128;
  ushort_t* PW2B  = PW1B  + 128*128;

  PJobs P;
  int nj = 0;
  auto add = [&](const float* src, ushort_t* dst, int N, int K, int Kpad, int rowofs, int Nw){
    P.j[nj].src = src; P.j[nj].dst = dst; P.j[nj].N = N; P.j[nj].K = K;
    P.j[nj].Kpad = Kpad; P.j[nj].rowofs = rowofs; P.j[nj].Nw = Nw; nj++;
  };
  add(enc_w1, W1B, 256, 115, 128, 0, 256);
  add(enc_w2, W2B, 128, 256, 256, 0, 128);
  add(proj_w, PWB, 128, 144, 160, 0, 128);
  for (int l = 0; l < NLD; l++)
    add(m_w_ig + (size_t)l*256*128, WIGB + (size_t)l*256*128, 256, 128, 128, 0, 256);
  for (int l = 0; l < NLD; l++){
    add(m_w_dt + (size_t)l*128*128, WDBCB + (size_t)l*144*128, 128, 128, 128, 0,   128);
    add(m_w_b  + (size_t)l*8*128,   WDBCB + (size_t)l*144*128,   8, 128, 128, 128,   8);
    add(m_w_c  + (size_t)l*8*128,   WDBCB + (size_t)l*144*128,   8, 128, 128, 136,   8);
  }
  for (int l = 0; l < NLD; l++)
    add(m_w_out + (size_t)l*128*128, WOUTB + (size_t)l*128*128, 128, 128, 128, 0, 128);
  add(pol_w1, PW1B, 128, 128, 128, 0, 128);
  add(pol_w2, PW2B,  19, 128, 128, 0,  32);

  k_prep<<<20*4, 256, 0, stream>>>(P);
  k_enc12p<<<NTOK/16, 256, 0, stream>>>(obs, W1B, enc_b1, enc_g1, enc_bb1,
      W2B, enc_b2, enc_g2, enc_bb2,
      emb, pact, PWB, proj_b, proj_g, proj_bb, X,
      m_ln_g, m_ln_b, WIGB, WDBCB, m_b_dt,
      XINb, Zb, DTb, BTu, CTu,
      m_a_log, HLA, PPA);

  const int carrygrid = BB*1024/64;    // 1024 blocks (2-level carry)
  const int scangrid  = NTOK/16;       // 2048 blocks x 256 thr

  // layer 0
  k_carry<<<carrygrid, 256, 0, stream>>>(HLA, PPA, h0);
  k_scan2p<<<scangrid, 256, 0, stream>>>(DTb, XINb, Zb, BTu, CTu,
      m_a_log, HLA, m_d, WOUTB, X,
      m_ln_g + 128, m_ln_b + 128,
      WIGB + (size_t)256*128, WDBCB + (size_t)144*128, m_b_dt + 128,
      m_a_log + 1024, HLB, PPB);
  // layer 1
  k_carry<<<carrygrid, 256, 0, stream>>>(HLB, PPB, h0 + (size_t)BB*1024);
  k_scan2p<<<scangrid, 256, 0, stream>>>(DTb, XINb, Zb, BTu, CTu,
      m_a_log + 1024, HLB, m_d + 128, WOUTB + (size_t)128*128, X,
      m_ln_g + 256, m_ln_b + 256,
      WIGB + (size_t)2*256*128, WDBCB + (size_t)2*144*128, m_b_dt + 256,
      m_a_log + 2048, HLA, PPA);
  // layer 2
  k_carry<<<carrygrid, 256, 0, stream>>>(HLA, PPA, h0 + (size_t)2*BB*1024);
  k_scan2h<<<scangrid, 256, 0, stream>>>(DTb, XINb, Zb, BTu, CTu,
      m_a_log + 2048, HLA, m_d + 256, WOUTB + (size_t)2*128*128, X,
      fn_g, fn_b, PW1B, pol_b1, pol_g, pol_bb, PW2B, pol_b2,
      (float*)d_out);
}